// Round 8
// baseline (237.667 us; speedup 1.0000x reference)
//
#include <hip/hip_runtime.h>
#include <cstdint>
#include <math.h>

#define TT 2048
#define CC 1024
#define HH 16
#define DH 64
#define BB 4
#define MM 8192   // B*T

typedef unsigned short u16;
typedef __bf16 bf16_t;
typedef bf16_t bf16x8 __attribute__((ext_vector_type(8)));
typedef float f32x4 __attribute__((ext_vector_type(4)));

// fp32 -> bf16 round-to-nearest-even (scalar)
static __device__ inline u16 f2bf(float f) {
    unsigned int u = __builtin_bit_cast(unsigned int, f);
    unsigned int lsb = (u >> 16) & 1u;
    u += 0x7fffu + lsb;
    return (u16)(u >> 16);
}

// packed 2xfp32 -> 2xbf16 (gfx950 v_cvt_pk_bf16_f32, RNE) — 1 op per 2 values
static __device__ inline unsigned int cvt_pk_bf16(float a, float b) {
    unsigned int r;
    asm volatile("v_cvt_pk_bf16_f32 %0, %1, %2" : "=v"(r) : "v"(a), "v"(b));
    return r;
}

// async 16B global->LDS (m97 pattern: LDS dest lane-linear 16B)
#define GLL16(gptr, lptr)                                                            \
    __builtin_amdgcn_global_load_lds(                                                \
        (__attribute__((address_space(1))) void*)(gptr),                             \
        (__attribute__((address_space(3))) void*)(lptr), 16, 0, 0)

// ---------------- prep kernels ----------------

__global__ void cast_x_kernel(const float* __restrict__ x, u16* __restrict__ xb, int n4) {
    int i = blockIdx.x * blockDim.x + threadIdx.x;
    if (i >= n4) return;
    float4 v = ((const float4*)x)[i];
    uint2 o;
    o.x = cvt_pk_bf16(v.x, v.y);
    o.y = cvt_pk_bf16(v.z, v.w);
    ((uint2*)xb)[i] = o;
}

// Tiled W[K][N] fp32 -> Wt[N][K] bf16 (coalesced both sides via LDS 32x32 tile).
__global__ void __launch_bounds__(256)
transpose_cast_kernel(const float* __restrict__ W, u16* __restrict__ Wt, int K, int N) {
    __shared__ u16 tile[32 * 34];   // [n][k], pad 34 u16 = 17 words (odd: conflict-free)
    const int tx = threadIdx.x & 31;
    const int ty = threadIdx.x >> 5;       // 0..7
    const int n0 = blockIdx.x * 32;
    const int k0 = blockIdx.y * 32;
#pragma unroll
    for (int i = 0; i < 4; ++i) {
        int k = ty + i * 8;                // 0..31
        tile[tx * 34 + k] = f2bf(W[(size_t)(k0 + k) * N + n0 + tx]);
    }
    __syncthreads();
    const int tx2 = threadIdx.x & 15;      // uint column: k = 2*tx2 (0..30)
    const int ty2 = threadIdx.x >> 4;      // 0..15
#pragma unroll
    for (int i = 0; i < 2; ++i) {
        int r = ty2 + i * 16;              // n-row 0..31
        *(unsigned int*)&Wt[(size_t)(n0 + r) * K + k0 + 2 * tx2] =
            *(unsigned int*)&tile[r * 34 + 2 * tx2];
    }
}

// ---------------- GEMM: C[M,N] = A[M,K] @ Bt[N,K]^T + bias ----------------
// ROUND-8 STRUCTURE + ROUND-16 LDS XOR SWIZZLE.
// r7 counters: SQ_LDS_BANK_CONFLICT = 6.29M/dispatch = +4 cyc per ds_read_b128
// (rows at 64B stride -> equal-parity rows share a 16-bank half; quads span
// only 16/32 banks). Fix (T2, both-sides-or-neither): logical k-column c of
// row r lives at physical column c ^ ((r>>1)&3). GLL16 dest stays LINEAR
// (hardware requirement); the permutation is applied to the per-lane GLOBAL
// source column (stage) and to the LDS read column. Read-side index
// (quad ^ ((l15>>1)&3)) is mt/wm-invariant. Each (parity,column) pair gets
// exactly 2 lanes/quarter -> uniform 2 accesses/bank = b128 minimum.
// MODE 0: A is y in [B,H,T,Dh] bf16; write fp32 C.
// MODE 1: A row-major [M,K] bf16; qkv scatter epilogue. V^T is stored with a
//   per-64-key-tile chunk permutation (4-key chunks [s3s2s1s0]->[s3,s1,s0,s2])
//   so the attention PV B-operand can be fed DIRECTLY from the QK output
//   registers (see attn_kernel notes).
template <int MODE>
__global__ void __launch_bounds__(256)
gemm_bt_kernel(const u16* __restrict__ A, const u16* __restrict__ Bt,
               const float* __restrict__ bias, float* __restrict__ Cout,
               u16* __restrict__ qws, u16* __restrict__ kws, u16* __restrict__ vtws,
               int Mdim, int Ndim, int Kdim) {
    __shared__ u16 As[2][128 * 32];
    __shared__ u16 Bs[2][128 * 32];

    const int tid  = threadIdx.x;
    const int w    = tid >> 6;
    const int lane = tid & 63;
    const int l15  = lane & 15;
    const int quad = lane >> 4;
    const int wm   = (w & 1) * 64;
    const int wn   = (w >> 1) * 64;
    const int m0   = blockIdx.y * 128;
    const int n0   = blockIdx.x * 128;

    const int row0  = tid >> 2;              // 0..63
    const int row1  = row0 + 64;             // 64..127 ((row1>>1)&3 == (row0>>1)&3)
    // swizzled k-column for staging: c_phys = tid&3, fetch c_log = c_phys ^ ((row>>1)&3)
    const int colsw = (((tid & 3) ^ ((row0 >> 1) & 3))) << 3;   // u16 units

    f32x4 acc[4][4];
#pragma unroll
    for (int i = 0; i < 4; ++i)
#pragma unroll
        for (int j = 0; j < 4; ++j) acc[i][j] = (f32x4){0.f, 0.f, 0.f, 0.f};

    auto stageA = [&](int buf, int kc) {
        if (MODE == 0) {
            int kcc = kc + colsw, h = kcc >> 6, d = kcc & 63;
            int m = m0 + row0, b = m >> 11, t = m & 2047;
            GLL16(&A[(((size_t)(b * HH + h) * TT + t) * DH) + d], &As[buf][tid * 8]);
            m = m0 + row1; b = m >> 11; t = m & 2047;
            GLL16(&A[(((size_t)(b * HH + h) * TT + t) * DH) + d], &As[buf][(tid + 256) * 8]);
        } else {
            GLL16(&A[(size_t)(m0 + row0) * Kdim + kc + colsw], &As[buf][tid * 8]);
            GLL16(&A[(size_t)(m0 + row1) * Kdim + kc + colsw], &As[buf][(tid + 256) * 8]);
        }
    };

    // prologue: stage tile 0 into buffer 0
    stageA(0, 0);
    GLL16(&Bt[(size_t)(n0 + row0) * Kdim + colsw], &Bs[0][tid * 8]);
    GLL16(&Bt[(size_t)(n0 + row1) * Kdim + colsw], &Bs[0][(tid + 256) * 8]);

    // swizzled read column (constant per lane; row base bits are multiples of 16)
    const int csw = (quad ^ ((l15 >> 1) & 3)) * 8;

    const int nsteps = Kdim >> 5;
    for (int it = 0; it < nsteps; ++it) {
        const int buf = it & 1;
        __syncthreads();   // publishes tile `it` (drains its GLL16s — issued a full step ago)

        if (it + 1 < nsteps) {
            const int nbuf = buf ^ 1;
            const int kc = (it + 1) << 5;
            stageA(nbuf, kc);
            GLL16(&Bt[(size_t)(n0 + row0) * Kdim + kc + colsw], &Bs[nbuf][tid * 8]);
            GLL16(&Bt[(size_t)(n0 + row1) * Kdim + kc + colsw], &Bs[nbuf][(tid + 256) * 8]);
        }

        bf16x8 af[4], bfm[4];
#pragma unroll
        for (int mt = 0; mt < 4; ++mt)
            af[mt] = *(const bf16x8*)&As[buf][(wm + mt * 16 + l15) * 32 + csw];
#pragma unroll
        for (int nt = 0; nt < 4; ++nt)
            bfm[nt] = *(const bf16x8*)&Bs[buf][(wn + nt * 16 + l15) * 32 + csw];
#pragma unroll
        for (int mt = 0; mt < 4; ++mt)
#pragma unroll
            for (int nt = 0; nt < 4; ++nt)
                acc[mt][nt] = __builtin_amdgcn_mfma_f32_16x16x32_bf16(
                    af[mt], bfm[nt], acc[mt][nt], 0, 0, 0);
    }

    // epilogue: D row = quad*4+r, col = l15
#pragma unroll
    for (int mt = 0; mt < 4; ++mt) {
        int mrow_base = m0 + wm + mt * 16 + quad * 4;
#pragma unroll
        for (int nt = 0; nt < 4; ++nt) {
            int ncol = n0 + wn + nt * 16 + l15;
            float bv = bias[ncol];
            if (MODE == 0) {
#pragma unroll
                for (int r = 0; r < 4; ++r)
                    Cout[(size_t)(mrow_base + r) * Ndim + ncol] = acc[mt][nt][r] + bv;
            } else {
                int which = ncol >> 10, c = ncol & 1023;
                int h = c >> 6, d = c & 63;
                if (which == 2) {
                    // V^T: r spans 4 consecutive t -> packed store, with the
                    // key-permutation folded in: 4-key chunk [s3s2s1s0] -> [s3,s1,s0,s2]
                    int b = mrow_base >> 11, t = mrow_base & 2047;
                    int bh = b * HH + h;
                    int ch = (t >> 2) & 15;
                    int chp = (ch & 8) | (((ch >> 1) & 1) << 2) | ((ch & 1) << 1) | ((ch >> 2) & 1);
                    int tp = (t & ~63) | (chp << 2);
                    uint2 pv;
                    pv.x = cvt_pk_bf16(acc[mt][nt][0] + bv, acc[mt][nt][1] + bv);
                    pv.y = cvt_pk_bf16(acc[mt][nt][2] + bv, acc[mt][nt][3] + bv);
                    *(uint2*)&vtws[((size_t)bh * DH + d) * TT + tp] = pv;
                } else {
#pragma unroll
                    for (int r = 0; r < 4; ++r) {
                        int mrow = mrow_base + r;
                        int b = mrow >> 11, t = mrow & 2047;
                        int bh = b * HH + h;
                        float val = acc[mt][nt][r] + bv;
                        if (which == 0) {
                            // fold softmax scale and log2(e) into Q: 0.125*log2e
                            qws[((size_t)bh * TT + t) * DH + d] = f2bf(val * 0.18033688f);
                        } else {
                            kws[((size_t)bh * TT + t) * DH + d] = f2bf(val);
                        }
                    }
                }
            }
        }
    }
}

// ---------------- flash attention v11: zero-LDS P path (r7-verified) ----------------
// passed r7 at ~<60us est (dropped out of top-5). Chain per tile:
// barrier -> K/V b128 reads -> QK MFMA -> mask/exp2/cvt_pk -> PV MFMA.
// P never touches LDS (key-permutation trick; V^T pre-permuted by GEMM).
__global__ void __launch_bounds__(256, 3)
attn_kernel(const u16* __restrict__ qws, const u16* __restrict__ kws,
            const u16* __restrict__ vtws, u16* __restrict__ yws) {
    __shared__ u16 Ks[2][64 * 68];   // K tile  [key][d], stride 68 u16 (bank-balanced)
    __shared__ u16 Vs[2][64 * 68];   // V^T tile [d][key-permuted]

    const int tid  = threadIdx.x;
    const int w    = tid >> 6;       // 0..3
    const int lane = tid & 63;
    const int l15  = lane & 15;
    const int quad = lane >> 4;
    const int bh   = blockIdx.x;     // fast index: co-locates same-bh blocks per XCD
    const int qt   = 15 - blockIdx.y;   // heavy tiles first

    const u16* Kbase = kws + (size_t)bh * TT * DH;
    const u16* Vbase = vtws + (size_t)bh * DH * TT;

    // staging: 256 threads x 32B each for K and V (fully coalesced)
    const int srow  = tid >> 2;          // 0..63
    const int sc16  = (tid & 3) << 4;    // 0,16,32,48 (u16 units)

    bf16x8 aones;
#pragma unroll
    for (int i = 0; i < 8; ++i) aones[i] = __builtin_bit_cast(bf16_t, (u16)0x3F80);

    const int q0     = qt * 128;
    const int qr0    = q0 + w * 32;    // this wave's 32 queries
    const int ntiles = (q0 + 128) >> 6;

    // Q fragments as B-operand (lane=query, contiguous d); scale+log2e folded
    const u16* Qp = qws + ((size_t)bh * TT + qr0) * DH;
    bf16x8 bqa[2], bqb[2];
#pragma unroll
    for (int kk = 0; kk < 2; ++kk) {
        bqa[kk] = *(const bf16x8*)&Qp[l15 * DH + kk * 32 + quad * 8];
        bqb[kk] = *(const bf16x8*)&Qp[(16 + l15) * DH + kk * 32 + quad * 8];
    }

    f32x4 o[2][4], ol[2];
#pragma unroll
    for (int qg = 0; qg < 2; ++qg) {
#pragma unroll
        for (int dt = 0; dt < 4; ++dt) o[qg][dt] = (f32x4){0.f, 0.f, 0.f, 0.f};
        ol[qg] = (f32x4){0.f, 0.f, 0.f, 0.f};
    }

    // prologue: tile 0 -> regs -> LDS[0]; tile 1 -> regs
    uint4 pk0 = *(const uint4*)&Kbase[(size_t)srow * DH + sc16];
    uint4 pk1 = *(const uint4*)&Kbase[(size_t)srow * DH + sc16 + 8];
    uint4 pv0 = *(const uint4*)&Vbase[(size_t)srow * TT + sc16];
    uint4 pv1 = *(const uint4*)&Vbase[(size_t)srow * TT + sc16 + 8];
    *(uint4*)&Ks[0][srow * 68 + sc16]     = pk0;
    *(uint4*)&Ks[0][srow * 68 + sc16 + 8] = pk1;
    *(uint4*)&Vs[0][srow * 68 + sc16]     = pv0;
    *(uint4*)&Vs[0][srow * 68 + sc16 + 8] = pv1;
    if (ntiles > 1) {
        pk0 = *(const uint4*)&Kbase[(size_t)(64 + srow) * DH + sc16];
        pk1 = *(const uint4*)&Kbase[(size_t)(64 + srow) * DH + sc16 + 8];
        pv0 = *(const uint4*)&Vbase[(size_t)srow * TT + 64 + sc16];
        pv1 = *(const uint4*)&Vbase[(size_t)srow * TT + 64 + sc16 + 8];
    }

    for (int it = 0; it < ntiles; ++it) {
        const int buf = it & 1;
        __syncthreads();   // publishes tile `it`; frees buffer buf^1

        if (it + 1 < ntiles) {
            *(uint4*)&Ks[buf ^ 1][srow * 68 + sc16]     = pk0;
            *(uint4*)&Ks[buf ^ 1][srow * 68 + sc16 + 8] = pk1;
            *(uint4*)&Vs[buf ^ 1][srow * 68 + sc16]     = pv0;
            *(uint4*)&Vs[buf ^ 1][srow * 68 + sc16 + 8] = pv1;
            if (it + 2 < ntiles) {
                int jn = (it + 2) << 6;
                pk0 = *(const uint4*)&Kbase[(size_t)(jn + srow) * DH + sc16];
                pk1 = *(const uint4*)&Kbase[(size_t)(jn + srow) * DH + sc16 + 8];
                pv0 = *(const uint4*)&Vbase[(size_t)srow * TT + jn + sc16];
                pv1 = *(const uint4*)&Vbase[(size_t)srow * TT + jn + sc16 + 8];
            }
        }

        const int j0 = it << 6;
        if (j0 > qr0 + 31) continue;   // fully masked for this wave (both q-groups)

        // ---- K fragments ONCE, reused by both q-groups ----
        bf16x8 ak[8];
#pragma unroll
        for (int kk = 0; kk < 2; ++kk)
#pragma unroll
            for (int kt = 0; kt < 4; ++kt)
                ak[kk * 4 + kt] =
                    *(const bf16x8*)&Ks[buf][(kt * 16 + l15) * 68 + kk * 32 + quad * 8];

        // ---- V fragments (natural b128 reads; permutation lives in vtws) ----
        bf16x8 avr[8];
#pragma unroll
        for (int kk = 0; kk < 2; ++kk)
#pragma unroll
            for (int dt = 0; dt < 4; ++dt)
                avr[kk * 4 + dt] =
                    *(const bf16x8*)&Vs[buf][(dt * 16 + l15) * 68 + kk * 32 + quad * 8];

        // ---- S^T = K @ Q^T for both q-groups ----
        f32x4 sa[4], sb[4];
#pragma unroll
        for (int kt = 0; kt < 4; ++kt) {
            sa[kt] = (f32x4){0.f, 0.f, 0.f, 0.f};
            sb[kt] = (f32x4){0.f, 0.f, 0.f, 0.f};
        }
#pragma unroll
        for (int kk = 0; kk < 2; ++kk)
#pragma unroll
            for (int kt = 0; kt < 4; ++kt)
                sa[kt] = __builtin_amdgcn_mfma_f32_16x16x32_bf16(ak[kk * 4 + kt], bqa[kk], sa[kt], 0, 0, 0);
#pragma unroll
        for (int kk = 0; kk < 2; ++kk)
#pragma unroll
            for (int kt = 0; kt < 4; ++kt)
                sb[kt] = __builtin_amdgcn_mfma_f32_16x16x32_bf16(ak[kk * 4 + kt], bqb[kk], sb[kt], 0, 0, 0);

        // causal mask (diagonal region only): key > query -> -inf
        if (j0 + 63 > qr0) {
            int qy0 = qr0 + l15;
            int qy1 = qr0 + 16 + l15;
#pragma unroll
            for (int kt = 0; kt < 4; ++kt)
#pragma unroll
                for (int r = 0; r < 4; ++r) {
                    int key = j0 + kt * 16 + quad * 4 + r;
                    if (key > qy0) sa[kt][r] = -INFINITY;
                    if (key > qy1) sb[kt][r] = -INFINITY;
                }
        }

        // ---- max-free softmax: p = exp2(s) ----
#pragma unroll
        for (int kt = 0; kt < 4; ++kt)
#pragma unroll
            for (int r = 0; r < 4; ++r) {
                sa[kt][r] = __builtin_amdgcn_exp2f(sa[kt][r]);
                sb[kt][r] = __builtin_amdgcn_exp2f(sb[kt][r]);
            }

        // ---- P -> PV B-operand DIRECTLY in-register: bp(kk) = pack(s[2kk],s[2kk+1]).
        // Slot->key bijection is matched by the permuted V^T layout. No LDS. ----
        uint4 ua0, ua1, ub0, ub1;
        ua0.x = cvt_pk_bf16(sa[0][0], sa[0][1]);
        ua0.y = cvt_pk_bf16(sa[0][2], sa[0][3]);
        ua0.z = cvt_pk_bf16(sa[1][0], sa[1][1]);
        ua0.w = cvt_pk_bf16(sa[1][2], sa[1][3]);
        ua1.x = cvt_pk_bf16(sa[2][0], sa[2][1]);
        ua1.y = cvt_pk_bf16(sa[2][2], sa[2][3]);
        ua1.z = cvt_pk_bf16(sa[3][0], sa[3][1]);
        ua1.w = cvt_pk_bf16(sa[3][2], sa[3][3]);
        ub0.x = cvt_pk_bf16(sb[0][0], sb[0][1]);
        ub0.y = cvt_pk_bf16(sb[0][2], sb[0][3]);
        ub0.z = cvt_pk_bf16(sb[1][0], sb[1][1]);
        ub0.w = cvt_pk_bf16(sb[1][2], sb[1][3]);
        ub1.x = cvt_pk_bf16(sb[2][0], sb[2][1]);
        ub1.y = cvt_pk_bf16(sb[2][2], sb[2][3]);
        ub1.z = cvt_pk_bf16(sb[3][0], sb[3][1]);
        ub1.w = cvt_pk_bf16(sb[3][2], sb[3][3]);
        bf16x8 bpa0 = __builtin_bit_cast(bf16x8, ua0);
        bf16x8 bpa1 = __builtin_bit_cast(bf16x8, ua1);
        bf16x8 bpb0 = __builtin_bit_cast(bf16x8, ub0);
        bf16x8 bpb1 = __builtin_bit_cast(bf16x8, ub1);

        // ---- O^T += V^T @ P^T ; l += ones @ P^T (fused row-sum) ----
#pragma unroll
        for (int dt = 0; dt < 4; ++dt)
            o[0][dt] = __builtin_amdgcn_mfma_f32_16x16x32_bf16(avr[dt], bpa0, o[0][dt], 0, 0, 0);
        ol[0] = __builtin_amdgcn_mfma_f32_16x16x32_bf16(aones, bpa0, ol[0], 0, 0, 0);
#pragma unroll
        for (int dt = 0; dt < 4; ++dt)
            o[0][dt] = __builtin_amdgcn_mfma_f32_16x16x32_bf16(avr[4 + dt], bpa1, o[0][dt], 0, 0, 0);
        ol[0] = __builtin_amdgcn_mfma_f32_16x16x32_bf16(aones, bpa1, ol[0], 0, 0, 0);
#pragma unroll
        for (int dt = 0; dt < 4; ++dt)
            o[1][dt] = __builtin_amdgcn_mfma_f32_16x16x32_bf16(avr[dt], bpb0, o[1][dt], 0, 0, 0);
        ol[1] = __builtin_amdgcn_mfma_f32_16x16x32_bf16(aones, bpb0, ol[1], 0, 0, 0);
#pragma unroll
        for (int dt = 0; dt < 4; ++dt)
            o[1][dt] = __builtin_amdgcn_mfma_f32_16x16x32_bf16(avr[4 + dt], bpb1, o[1][dt], 0, 0, 0);
        ol[1] = __builtin_amdgcn_mfma_f32_16x16x32_bf16(aones, bpb1, ol[1], 0, 0, 0);
    }

    // ---- normalize + store O^T to y[B,H,T,Dh] (coalesced) ----
#pragma unroll
    for (int qg = 0; qg < 2; ++qg) {
        float rinv = __builtin_amdgcn_rcpf(ol[qg][0]);   // l[query]; ~1ulp ok at bf16 out
        int t = qr0 + qg * 16 + l15;
#pragma unroll
        for (int dt = 0; dt < 4; ++dt) {
            uint2 yv;
            yv.x = cvt_pk_bf16(o[qg][dt][0] * rinv, o[qg][dt][1] * rinv);
            yv.y = cvt_pk_bf16(o[qg][dt][2] * rinv, o[qg][dt][3] * rinv);
            *(uint2*)&yws[((size_t)bh * TT + t) * DH + dt * 16 + quad * 4] = yv;
        }
    }
}

// ---------------- launch ----------------

extern "C" void kernel_launch(void* const* d_in, const int* in_sizes, int n_in,
                              void* d_out, int out_size, void* d_ws, size_t ws_size,
                              hipStream_t stream) {
    const float* x     = (const float*)d_in[0];
    const float* W_qkv = (const float*)d_in[1];
    const float* b_qkv = (const float*)d_in[2];
    const float* W_out = (const float*)d_in[3];
    const float* b_out = (const float*)d_in[4];
    float* out = (float*)d_out;

    char* ws = (char*)d_ws;
    u16* xb   = (u16*)ws; ws += (size_t)MM * CC * 2;       // x bf16        16 MB
    u16* wqt  = (u16*)ws; ws += (size_t)3 * CC * CC * 2;   // W_qkv^T bf16   6 MB
    u16* wot  = (u16*)ws; ws += (size_t)CC * CC * 2;       // W_out^T bf16   2 MB
    u16* qws  = (u16*)ws; ws += (size_t)MM * CC * 2;       // Q [B,H,T,Dh]  16 MB
    u16* kws  = (u16*)ws; ws += (size_t)MM * CC * 2;       // K [B,H,T,Dh]  16 MB
    u16* vtws = (u16*)ws; ws += (size_t)MM * CC * 2;       // V^T [B,H,Dh,T] (key-permuted) 16 MB
    u16* yws  = (u16*)ws; ws += (size_t)MM * CC * 2;       // y [B,H,T,Dh]  16 MB

    cast_x_kernel<<<(MM * CC / 4) / 256, 256, 0, stream>>>(x, xb, MM * CC / 4);
    transpose_cast_kernel<<<dim3(3 * CC / 32, CC / 32), 256, 0, stream>>>(W_qkv, wqt, CC, 3 * CC);
    transpose_cast_kernel<<<dim3(CC / 32, CC / 32), 256, 0, stream>>>(W_out, wot, CC, CC);

    gemm_bt_kernel<1><<<dim3(24, 64), 256, 0, stream>>>(
        xb, wqt, b_qkv, nullptr, qws, kws, vtws, MM, 3 * CC, CC);

    attn_kernel<<<dim3(BB * HH, 16), 256, 0, stream>>>(qws, kws, vtws, yws);

    gemm_bt_kernel<0><<<dim3(8, 64), 256, 0, stream>>>(
        yws, wot, b_out, out, nullptr, nullptr, nullptr, MM, CC, CC);
}

// Round 9
// 237.113 us; speedup vs baseline: 1.0023x; 1.0023x over previous
//
#include <hip/hip_runtime.h>
#include <cstdint>
#include <math.h>

#define TT 2048
#define CC 1024
#define HH 16
#define DH 64
#define BB 4
#define MM 8192   // B*T

typedef unsigned short u16;
typedef __bf16 bf16_t;
typedef bf16_t bf16x8 __attribute__((ext_vector_type(8)));
typedef float f32x4 __attribute__((ext_vector_type(4)));

// fp32 -> bf16 round-to-nearest-even (scalar)
static __device__ inline u16 f2bf(float f) {
    unsigned int u = __builtin_bit_cast(unsigned int, f);
    unsigned int lsb = (u >> 16) & 1u;
    u += 0x7fffu + lsb;
    return (u16)(u >> 16);
}

// packed 2xfp32 -> 2xbf16 (gfx950 v_cvt_pk_bf16_f32, RNE) — 1 op per 2 values
static __device__ inline unsigned int cvt_pk_bf16(float a, float b) {
    unsigned int r;
    asm volatile("v_cvt_pk_bf16_f32 %0, %1, %2" : "=v"(r) : "v"(a), "v"(b));
    return r;
}

// async 16B global->LDS (m97 pattern: LDS dest lane-linear 16B)
#define GLL16(gptr, lptr)                                                            \
    __builtin_amdgcn_global_load_lds(                                                \
        (__attribute__((address_space(1))) void*)(gptr),                             \
        (__attribute__((address_space(3))) void*)(lptr), 16, 0, 0)

// ---------------- prep kernels ----------------

__global__ void cast_x_kernel(const float* __restrict__ x, u16* __restrict__ xb, int n4) {
    int i = blockIdx.x * blockDim.x + threadIdx.x;
    if (i >= n4) return;
    float4 v = ((const float4*)x)[i];
    uint2 o;
    o.x = cvt_pk_bf16(v.x, v.y);
    o.y = cvt_pk_bf16(v.z, v.w);
    ((uint2*)xb)[i] = o;
}

// Tiled W[K][N] fp32 -> Wt[N][K] bf16 (coalesced both sides via LDS 32x32 tile).
__global__ void __launch_bounds__(256)
transpose_cast_kernel(const float* __restrict__ W, u16* __restrict__ Wt, int K, int N) {
    __shared__ u16 tile[32 * 34];   // [n][k], pad 34 u16 = 17 words (odd: conflict-free)
    const int tx = threadIdx.x & 31;
    const int ty = threadIdx.x >> 5;       // 0..7
    const int n0 = blockIdx.x * 32;
    const int k0 = blockIdx.y * 32;
#pragma unroll
    for (int i = 0; i < 4; ++i) {
        int k = ty + i * 8;                // 0..31
        tile[tx * 34 + k] = f2bf(W[(size_t)(k0 + k) * N + n0 + tx]);
    }
    __syncthreads();
    const int tx2 = threadIdx.x & 15;      // uint column: k = 2*tx2 (0..30)
    const int ty2 = threadIdx.x >> 4;      // 0..15
#pragma unroll
    for (int i = 0; i < 2; ++i) {
        int r = ty2 + i * 16;              // n-row 0..31
        *(unsigned int*)&Wt[(size_t)(n0 + r) * K + k0 + 2 * tx2] =
            *(unsigned int*)&tile[r * 34 + 2 * tx2];
    }
}

// ---------------- GEMM: C[M,N] = A[M,K] @ Bt[N,K]^T + bias ----------------
// ROUND-17: 3-BUFFER STAGING + COUNTED VMCNT (T4). r8 showed conflicts=0 but
// dur flat -> the stall is __syncthreads' full vmcnt(0) drain per k-step (the
// documented m97-structure ceiling). New schedule per k-step:
//   s_waitcnt vmcnt(4)   (drain tile it's 4 vmem ops; tile it+1's stay in flight)
//   s_barrier            (all waves' tile-it data published in LDS)
//   stage tile it+2 -> buf (it+2)%3   (readers of that buf finished pre-barrier)
//   MFMA compute on buf it%3
// Loads get TWO compute phases of latency cover; pipeline never drains.
// + r16 LDS XOR swizzle (conflict-free, verified 6.29M->0).
// MODE 0: A is y in [B,H,T,Dh] bf16; write fp32 C.
// MODE 1: A row-major [M,K] bf16; qkv scatter epilogue. V^T stored with the
//   key-chunk permutation for the attn zero-LDS-P path.
template <int MODE>
__global__ void __launch_bounds__(256)
gemm_bt_kernel(const u16* __restrict__ A, const u16* __restrict__ Bt,
               const float* __restrict__ bias, float* __restrict__ Cout,
               u16* __restrict__ qws, u16* __restrict__ kws, u16* __restrict__ vtws,
               int Mdim, int Ndim, int Kdim) {
    __shared__ u16 As[3][128 * 32];
    __shared__ u16 Bs[3][128 * 32];

    const int tid  = threadIdx.x;
    const int w    = tid >> 6;
    const int lane = tid & 63;
    const int l15  = lane & 15;
    const int quad = lane >> 4;
    const int wm   = (w & 1) * 64;
    const int wn   = (w >> 1) * 64;
    const int m0   = blockIdx.y * 128;
    const int n0   = blockIdx.x * 128;

    const int row0  = tid >> 2;              // 0..63
    const int row1  = row0 + 64;             // 64..127 ((row1>>1)&3 == (row0>>1)&3)
    // swizzled k-column for staging: c_phys = tid&3, fetch c_log = c_phys ^ ((row>>1)&3)
    const int colsw = (((tid & 3) ^ ((row0 >> 1) & 3))) << 3;   // u16 units

    f32x4 acc[4][4];
#pragma unroll
    for (int i = 0; i < 4; ++i)
#pragma unroll
        for (int j = 0; j < 4; ++j) acc[i][j] = (f32x4){0.f, 0.f, 0.f, 0.f};

    auto stageA = [&](int buf, int kc) {
        if (MODE == 0) {
            int kcc = kc + colsw, h = kcc >> 6, d = kcc & 63;
            int m = m0 + row0, b = m >> 11, t = m & 2047;
            GLL16(&A[(((size_t)(b * HH + h) * TT + t) * DH) + d], &As[buf][tid * 8]);
            m = m0 + row1; b = m >> 11; t = m & 2047;
            GLL16(&A[(((size_t)(b * HH + h) * TT + t) * DH) + d], &As[buf][(tid + 256) * 8]);
        } else {
            GLL16(&A[(size_t)(m0 + row0) * Kdim + kc + colsw], &As[buf][tid * 8]);
            GLL16(&A[(size_t)(m0 + row1) * Kdim + kc + colsw], &As[buf][(tid + 256) * 8]);
        }
    };
    auto stageB = [&](int buf, int kc) {
        GLL16(&Bt[(size_t)(n0 + row0) * Kdim + kc + colsw], &Bs[buf][tid * 8]);
        GLL16(&Bt[(size_t)(n0 + row1) * Kdim + kc + colsw], &Bs[buf][(tid + 256) * 8]);
    };

    const int nsteps = Kdim >> 5;
    // prologue: stage tiles 0 and 1 (8 vmem ops/wave in flight)
    stageA(0, 0);
    stageB(0, 0);
    if (nsteps > 1) { stageA(1, 32); stageB(1, 32); }

    // swizzled read column (constant per lane; row base bits are multiples of 16)
    const int csw = (quad ^ ((l15 >> 1) & 3)) * 8;

    int buf = 0, stg = 2;
    for (int it = 0; it < nsteps; ++it) {
        // drain ONLY tile it's 4 vmem ops (tile it+1's 4 remain in flight),
        // then rendezvous: after the barrier every wave's tile-it data is in LDS.
        if (it + 1 < nsteps) asm volatile("s_waitcnt vmcnt(4)" ::: "memory");
        else                 asm volatile("s_waitcnt vmcnt(0)" ::: "memory");
        __builtin_amdgcn_s_barrier();
        __builtin_amdgcn_sched_barrier(0);

        if (it + 2 < nsteps) {
            const int kc = (it + 2) << 5;
            stageA(stg, kc);
            stageB(stg, kc);
        }

        bf16x8 af[4], bfm[4];
#pragma unroll
        for (int mt = 0; mt < 4; ++mt)
            af[mt] = *(const bf16x8*)&As[buf][(wm + mt * 16 + l15) * 32 + csw];
#pragma unroll
        for (int nt = 0; nt < 4; ++nt)
            bfm[nt] = *(const bf16x8*)&Bs[buf][(wn + nt * 16 + l15) * 32 + csw];
#pragma unroll
        for (int mt = 0; mt < 4; ++mt)
#pragma unroll
            for (int nt = 0; nt < 4; ++nt)
                acc[mt][nt] = __builtin_amdgcn_mfma_f32_16x16x32_bf16(
                    af[mt], bfm[nt], acc[mt][nt], 0, 0, 0);

        buf = (buf == 2) ? 0 : buf + 1;
        stg = (stg == 2) ? 0 : stg + 1;
    }

    // epilogue: D row = quad*4+r, col = l15
#pragma unroll
    for (int mt = 0; mt < 4; ++mt) {
        int mrow_base = m0 + wm + mt * 16 + quad * 4;
#pragma unroll
        for (int nt = 0; nt < 4; ++nt) {
            int ncol = n0 + wn + nt * 16 + l15;
            float bv = bias[ncol];
            if (MODE == 0) {
#pragma unroll
                for (int r = 0; r < 4; ++r)
                    Cout[(size_t)(mrow_base + r) * Ndim + ncol] = acc[mt][nt][r] + bv;
            } else {
                int which = ncol >> 10, c = ncol & 1023;
                int h = c >> 6, d = c & 63;
                if (which == 2) {
                    // V^T: r spans 4 consecutive t -> packed store, with the
                    // key-permutation folded in: 4-key chunk [s3s2s1s0] -> [s3,s1,s0,s2]
                    int b = mrow_base >> 11, t = mrow_base & 2047;
                    int bh = b * HH + h;
                    int ch = (t >> 2) & 15;
                    int chp = (ch & 8) | (((ch >> 1) & 1) << 2) | ((ch & 1) << 1) | ((ch >> 2) & 1);
                    int tp = (t & ~63) | (chp << 2);
                    uint2 pv;
                    pv.x = cvt_pk_bf16(acc[mt][nt][0] + bv, acc[mt][nt][1] + bv);
                    pv.y = cvt_pk_bf16(acc[mt][nt][2] + bv, acc[mt][nt][3] + bv);
                    *(uint2*)&vtws[((size_t)bh * DH + d) * TT + tp] = pv;
                } else {
#pragma unroll
                    for (int r = 0; r < 4; ++r) {
                        int mrow = mrow_base + r;
                        int b = mrow >> 11, t = mrow & 2047;
                        int bh = b * HH + h;
                        float val = acc[mt][nt][r] + bv;
                        if (which == 0) {
                            // fold softmax scale and log2(e) into Q: 0.125*log2e
                            qws[((size_t)bh * TT + t) * DH + d] = f2bf(val * 0.18033688f);
                        } else {
                            kws[((size_t)bh * TT + t) * DH + d] = f2bf(val);
                        }
                    }
                }
            }
        }
    }
}

// ---------------- flash attention v11: zero-LDS P path (r7-verified) ----------------
// passed r7 at ~<60us est (dropped out of top-5). Chain per tile:
// barrier -> K/V b128 reads -> QK MFMA -> mask/exp2/cvt_pk -> PV MFMA.
// P never touches LDS (key-permutation trick; V^T pre-permuted by GEMM).
__global__ void __launch_bounds__(256, 3)
attn_kernel(const u16* __restrict__ qws, const u16* __restrict__ kws,
            const u16* __restrict__ vtws, u16* __restrict__ yws) {
    __shared__ u16 Ks[2][64 * 68];   // K tile  [key][d], stride 68 u16 (bank-balanced)
    __shared__ u16 Vs[2][64 * 68];   // V^T tile [d][key-permuted]

    const int tid  = threadIdx.x;
    const int w    = tid >> 6;       // 0..3
    const int lane = tid & 63;
    const int l15  = lane & 15;
    const int quad = lane >> 4;
    const int bh   = blockIdx.x;     // fast index: co-locates same-bh blocks per XCD
    const int qt   = 15 - blockIdx.y;   // heavy tiles first

    const u16* Kbase = kws + (size_t)bh * TT * DH;
    const u16* Vbase = vtws + (size_t)bh * DH * TT;

    // staging: 256 threads x 32B each for K and V (fully coalesced)
    const int srow  = tid >> 2;          // 0..63
    const int sc16  = (tid & 3) << 4;    // 0,16,32,48 (u16 units)

    bf16x8 aones;
#pragma unroll
    for (int i = 0; i < 8; ++i) aones[i] = __builtin_bit_cast(bf16_t, (u16)0x3F80);

    const int q0     = qt * 128;
    const int qr0    = q0 + w * 32;    // this wave's 32 queries
    const int ntiles = (q0 + 128) >> 6;

    // Q fragments as B-operand (lane=query, contiguous d); scale+log2e folded
    const u16* Qp = qws + ((size_t)bh * TT + qr0) * DH;
    bf16x8 bqa[2], bqb[2];
#pragma unroll
    for (int kk = 0; kk < 2; ++kk) {
        bqa[kk] = *(const bf16x8*)&Qp[l15 * DH + kk * 32 + quad * 8];
        bqb[kk] = *(const bf16x8*)&Qp[(16 + l15) * DH + kk * 32 + quad * 8];
    }

    f32x4 o[2][4], ol[2];
#pragma unroll
    for (int qg = 0; qg < 2; ++qg) {
#pragma unroll
        for (int dt = 0; dt < 4; ++dt) o[qg][dt] = (f32x4){0.f, 0.f, 0.f, 0.f};
        ol[qg] = (f32x4){0.f, 0.f, 0.f, 0.f};
    }

    // prologue: tile 0 -> regs -> LDS[0]; tile 1 -> regs
    uint4 pk0 = *(const uint4*)&Kbase[(size_t)srow * DH + sc16];
    uint4 pk1 = *(const uint4*)&Kbase[(size_t)srow * DH + sc16 + 8];
    uint4 pv0 = *(const uint4*)&Vbase[(size_t)srow * TT + sc16];
    uint4 pv1 = *(const uint4*)&Vbase[(size_t)srow * TT + sc16 + 8];
    *(uint4*)&Ks[0][srow * 68 + sc16]     = pk0;
    *(uint4*)&Ks[0][srow * 68 + sc16 + 8] = pk1;
    *(uint4*)&Vs[0][srow * 68 + sc16]     = pv0;
    *(uint4*)&Vs[0][srow * 68 + sc16 + 8] = pv1;
    if (ntiles > 1) {
        pk0 = *(const uint4*)&Kbase[(size_t)(64 + srow) * DH + sc16];
        pk1 = *(const uint4*)&Kbase[(size_t)(64 + srow) * DH + sc16 + 8];
        pv0 = *(const uint4*)&Vbase[(size_t)srow * TT + 64 + sc16];
        pv1 = *(const uint4*)&Vbase[(size_t)srow * TT + 64 + sc16 + 8];
    }

    for (int it = 0; it < ntiles; ++it) {
        const int buf = it & 1;
        __syncthreads();   // publishes tile `it`; frees buffer buf^1

        if (it + 1 < ntiles) {
            *(uint4*)&Ks[buf ^ 1][srow * 68 + sc16]     = pk0;
            *(uint4*)&Ks[buf ^ 1][srow * 68 + sc16 + 8] = pk1;
            *(uint4*)&Vs[buf ^ 1][srow * 68 + sc16]     = pv0;
            *(uint4*)&Vs[buf ^ 1][srow * 68 + sc16 + 8] = pv1;
            if (it + 2 < ntiles) {
                int jn = (it + 2) << 6;
                pk0 = *(const uint4*)&Kbase[(size_t)(jn + srow) * DH + sc16];
                pk1 = *(const uint4*)&Kbase[(size_t)(jn + srow) * DH + sc16 + 8];
                pv0 = *(const uint4*)&Vbase[(size_t)srow * TT + jn + sc16];
                pv1 = *(const uint4*)&Vbase[(size_t)srow * TT + jn + sc16 + 8];
            }
        }

        const int j0 = it << 6;
        if (j0 > qr0 + 31) continue;   // fully masked for this wave (both q-groups)

        // ---- K fragments ONCE, reused by both q-groups ----
        bf16x8 ak[8];
#pragma unroll
        for (int kk = 0; kk < 2; ++kk)
#pragma unroll
            for (int kt = 0; kt < 4; ++kt)
                ak[kk * 4 + kt] =
                    *(const bf16x8*)&Ks[buf][(kt * 16 + l15) * 68 + kk * 32 + quad * 8];

        // ---- V fragments (natural b128 reads; permutation lives in vtws) ----
        bf16x8 avr[8];
#pragma unroll
        for (int kk = 0; kk < 2; ++kk)
#pragma unroll
            for (int dt = 0; dt < 4; ++dt)
                avr[kk * 4 + dt] =
                    *(const bf16x8*)&Vs[buf][(dt * 16 + l15) * 68 + kk * 32 + quad * 8];

        // ---- S^T = K @ Q^T for both q-groups ----
        f32x4 sa[4], sb[4];
#pragma unroll
        for (int kt = 0; kt < 4; ++kt) {
            sa[kt] = (f32x4){0.f, 0.f, 0.f, 0.f};
            sb[kt] = (f32x4){0.f, 0.f, 0.f, 0.f};
        }
#pragma unroll
        for (int kk = 0; kk < 2; ++kk)
#pragma unroll
            for (int kt = 0; kt < 4; ++kt)
                sa[kt] = __builtin_amdgcn_mfma_f32_16x16x32_bf16(ak[kk * 4 + kt], bqa[kk], sa[kt], 0, 0, 0);
#pragma unroll
        for (int kk = 0; kk < 2; ++kk)
#pragma unroll
            for (int kt = 0; kt < 4; ++kt)
                sb[kt] = __builtin_amdgcn_mfma_f32_16x16x32_bf16(ak[kk * 4 + kt], bqb[kk], sb[kt], 0, 0, 0);

        // causal mask (diagonal region only): key > query -> -inf
        if (j0 + 63 > qr0) {
            int qy0 = qr0 + l15;
            int qy1 = qr0 + 16 + l15;
#pragma unroll
            for (int kt = 0; kt < 4; ++kt)
#pragma unroll
                for (int r = 0; r < 4; ++r) {
                    int key = j0 + kt * 16 + quad * 4 + r;
                    if (key > qy0) sa[kt][r] = -INFINITY;
                    if (key > qy1) sb[kt][r] = -INFINITY;
                }
        }

        // ---- max-free softmax: p = exp2(s) ----
#pragma unroll
        for (int kt = 0; kt < 4; ++kt)
#pragma unroll
            for (int r = 0; r < 4; ++r) {
                sa[kt][r] = __builtin_amdgcn_exp2f(sa[kt][r]);
                sb[kt][r] = __builtin_amdgcn_exp2f(sb[kt][r]);
            }

        // ---- P -> PV B-operand DIRECTLY in-register: bp(kk) = pack(s[2kk],s[2kk+1]).
        // Slot->key bijection is matched by the permuted V^T layout. No LDS. ----
        uint4 ua0, ua1, ub0, ub1;
        ua0.x = cvt_pk_bf16(sa[0][0], sa[0][1]);
        ua0.y = cvt_pk_bf16(sa[0][2], sa[0][3]);
        ua0.z = cvt_pk_bf16(sa[1][0], sa[1][1]);
        ua0.w = cvt_pk_bf16(sa[1][2], sa[1][3]);
        ua1.x = cvt_pk_bf16(sa[2][0], sa[2][1]);
        ua1.y = cvt_pk_bf16(sa[2][2], sa[2][3]);
        ua1.z = cvt_pk_bf16(sa[3][0], sa[3][1]);
        ua1.w = cvt_pk_bf16(sa[3][2], sa[3][3]);
        ub0.x = cvt_pk_bf16(sb[0][0], sb[0][1]);
        ub0.y = cvt_pk_bf16(sb[0][2], sb[0][3]);
        ub0.z = cvt_pk_bf16(sb[1][0], sb[1][1]);
        ub0.w = cvt_pk_bf16(sb[1][2], sb[1][3]);
        ub1.x = cvt_pk_bf16(sb[2][0], sb[2][1]);
        ub1.y = cvt_pk_bf16(sb[2][2], sb[2][3]);
        ub1.z = cvt_pk_bf16(sb[3][0], sb[3][1]);
        ub1.w = cvt_pk_bf16(sb[3][2], sb[3][3]);
        bf16x8 bpa0 = __builtin_bit_cast(bf16x8, ua0);
        bf16x8 bpa1 = __builtin_bit_cast(bf16x8, ua1);
        bf16x8 bpb0 = __builtin_bit_cast(bf16x8, ub0);
        bf16x8 bpb1 = __builtin_bit_cast(bf16x8, ub1);

        // ---- O^T += V^T @ P^T ; l += ones @ P^T (fused row-sum) ----
#pragma unroll
        for (int dt = 0; dt < 4; ++dt)
            o[0][dt] = __builtin_amdgcn_mfma_f32_16x16x32_bf16(avr[dt], bpa0, o[0][dt], 0, 0, 0);
        ol[0] = __builtin_amdgcn_mfma_f32_16x16x32_bf16(aones, bpa0, ol[0], 0, 0, 0);
#pragma unroll
        for (int dt = 0; dt < 4; ++dt)
            o[0][dt] = __builtin_amdgcn_mfma_f32_16x16x32_bf16(avr[4 + dt], bpa1, o[0][dt], 0, 0, 0);
        ol[0] = __builtin_amdgcn_mfma_f32_16x16x32_bf16(aones, bpa1, ol[0], 0, 0, 0);
#pragma unroll
        for (int dt = 0; dt < 4; ++dt)
            o[1][dt] = __builtin_amdgcn_mfma_f32_16x16x32_bf16(avr[dt], bpb0, o[1][dt], 0, 0, 0);
        ol[1] = __builtin_amdgcn_mfma_f32_16x16x32_bf16(aones, bpb0, ol[1], 0, 0, 0);
#pragma unroll
        for (int dt = 0; dt < 4; ++dt)
            o[1][dt] = __builtin_amdgcn_mfma_f32_16x16x32_bf16(avr[4 + dt], bpb1, o[1][dt], 0, 0, 0);
        ol[1] = __builtin_amdgcn_mfma_f32_16x16x32_bf16(aones, bpb1, ol[1], 0, 0, 0);
    }

    // ---- normalize + store O^T to y[B,H,T,Dh] (coalesced) ----
#pragma unroll
    for (int qg = 0; qg < 2; ++qg) {
        float rinv = __builtin_amdgcn_rcpf(ol[qg][0]);   // l[query]; ~1ulp ok at bf16 out
        int t = qr0 + qg * 16 + l15;
#pragma unroll
        for (int dt = 0; dt < 4; ++dt) {
            uint2 yv;
            yv.x = cvt_pk_bf16(o[qg][dt][0] * rinv, o[qg][dt][1] * rinv);
            yv.y = cvt_pk_bf16(o[qg][dt][2] * rinv, o[qg][dt][3] * rinv);
            *(uint2*)&yws[((size_t)bh * TT + t) * DH + dt * 16 + quad * 4] = yv;
        }
    }
}

// ---------------- launch ----------------

extern "C" void kernel_launch(void* const* d_in, const int* in_sizes, int n_in,
                              void* d_out, int out_size, void* d_ws, size_t ws_size,
                              hipStream_t stream) {
    const float* x     = (const float*)d_in[0];
    const float* W_qkv = (const float*)d_in[1];
    const float* b_qkv = (const float*)d_in[2];
    const float* W_out = (const float*)d_in[3];
    const float* b_out = (const float*)d_in[4];
    float* out = (float*)d_out;

    char* ws = (char*)d_ws;
    u16* xb   = (u16*)ws; ws += (size_t)MM * CC * 2;       // x bf16        16 MB
    u16* wqt  = (u16*)ws; ws += (size_t)3 * CC * CC * 2;   // W_qkv^T bf16   6 MB
    u16* wot  = (u16*)ws; ws += (size_t)CC * CC * 2;       // W_out^T bf16   2 MB
    u16* qws  = (u16*)ws; ws += (size_t)MM * CC * 2;       // Q [B,H,T,Dh]  16 MB
    u16* kws  = (u16*)ws; ws += (size_t)MM * CC * 2;       // K [B,H,T,Dh]  16 MB
    u16* vtws = (u16*)ws; ws += (size_t)MM * CC * 2;       // V^T [B,H,Dh,T] (key-permuted) 16 MB
    u16* yws  = (u16*)ws; ws += (size_t)MM * CC * 2;       // y [B,H,T,Dh]  16 MB

    cast_x_kernel<<<(MM * CC / 4) / 256, 256, 0, stream>>>(x, xb, MM * CC / 4);
    transpose_cast_kernel<<<dim3(3 * CC / 32, CC / 32), 256, 0, stream>>>(W_qkv, wqt, CC, 3 * CC);
    transpose_cast_kernel<<<dim3(CC / 32, CC / 32), 256, 0, stream>>>(W_out, wot, CC, CC);

    gemm_bt_kernel<1><<<dim3(24, 64), 256, 0, stream>>>(
        xb, wqt, b_qkv, nullptr, qws, kws, vtws, MM, 3 * CC, CC);

    attn_kernel<<<dim3(BB * HH, 16), 256, 0, stream>>>(qws, kws, vtws, yws);

    gemm_bt_kernel<0><<<dim3(8, 64), 256, 0, stream>>>(
        yws, wot, b_out, out, nullptr, nullptr, nullptr, MM, CC, CC);
}

// Round 10
// 233.735 us; speedup vs baseline: 1.0168x; 1.0145x over previous
//
#include <hip/hip_runtime.h>
#include <cstdint>
#include <math.h>

#define TT 2048
#define CC 1024
#define HH 16
#define DH 64
#define BB 4
#define MM 8192   // B*T

typedef unsigned short u16;
typedef __bf16 bf16_t;
typedef bf16_t bf16x8 __attribute__((ext_vector_type(8)));
typedef float f32x4 __attribute__((ext_vector_type(4)));

// fp32 -> bf16 round-to-nearest-even (scalar)
static __device__ inline u16 f2bf(float f) {
    unsigned int u = __builtin_bit_cast(unsigned int, f);
    unsigned int lsb = (u >> 16) & 1u;
    u += 0x7fffu + lsb;
    return (u16)(u >> 16);
}

// packed 2xfp32 -> 2xbf16 (gfx950 v_cvt_pk_bf16_f32, RNE) — 1 op per 2 values
static __device__ inline unsigned int cvt_pk_bf16(float a, float b) {
    unsigned int r;
    asm volatile("v_cvt_pk_bf16_f32 %0, %1, %2" : "=v"(r) : "v"(a), "v"(b));
    return r;
}

// async 16B global->LDS (m97 pattern: LDS dest lane-linear 16B)
#define GLL16(gptr, lptr)                                                            \
    __builtin_amdgcn_global_load_lds(                                                \
        (__attribute__((address_space(1))) void*)(gptr),                             \
        (__attribute__((address_space(3))) void*)(lptr), 16, 0, 0)

// ---------------- fused prep kernel ----------------
// ROUND-18: one launch instead of three (cast_x + transpose W_qkv + transpose
// W_out). Budget arithmetic across r2/r4/r7/r8 shows a stable ~60us gap
// between sum(dispatch durs) and total -> ~10us/launch dispatch overhead.
// Jobs are independent; blockIdx partitions them. All blocks take a uniform
// branch (bid is wave-uniform), so the early return never splits a block.
__global__ void __launch_bounds__(256)
prep_kernel(const float* __restrict__ x, u16* __restrict__ xb,
            const float* __restrict__ Wq, u16* __restrict__ wqt,
            const float* __restrict__ Wo, u16* __restrict__ wot) {
    const int bid = blockIdx.x;
    if (bid < 8192) {                       // cast x: 8192 blocks x 256 x float4
        int i = bid * 256 + threadIdx.x;
        float4 v = ((const float4*)x)[i];
        uint2 o;
        o.x = cvt_pk_bf16(v.x, v.y);
        o.y = cvt_pk_bf16(v.z, v.w);
        ((uint2*)xb)[i] = o;
        return;
    }
    // transpose+cast W[K][N] -> Wt[N][K] via 32x32 LDS tile (pad 34: odd words)
    __shared__ u16 tile[32 * 34];
    const float* W; u16* Wt; int N, n0, k0;
    if (bid < 8192 + 3072) {                // W_qkv: N=3072 -> 96 x 32 blocks
        int idx = bid - 8192;
        W = Wq; Wt = wqt; N = 3 * CC;
        n0 = (idx % 96) * 32; k0 = (idx / 96) * 32;
    } else {                                // W_out: N=1024 -> 32 x 32 blocks
        int idx = bid - 11264;
        W = Wo; Wt = wot; N = CC;
        n0 = (idx % 32) * 32; k0 = (idx / 32) * 32;
    }
    const int tx = threadIdx.x & 31;
    const int ty = threadIdx.x >> 5;        // 0..7
#pragma unroll
    for (int i = 0; i < 4; ++i) {
        int k = ty + i * 8;                 // 0..31
        tile[tx * 34 + k] = f2bf(W[(size_t)(k0 + k) * N + n0 + tx]);
    }
    __syncthreads();
    const int tx2 = threadIdx.x & 15;       // uint column: k = 2*tx2
    const int ty2 = threadIdx.x >> 4;       // 0..15
#pragma unroll
    for (int i = 0; i < 2; ++i) {
        int r = ty2 + i * 16;               // n-row 0..31
        *(unsigned int*)&Wt[(size_t)(n0 + r) * CC + k0 + 2 * tx2] =
            *(unsigned int*)&tile[r * 34 + 2 * tx2];
    }
}

// ---------------- GEMM: C[M,N] = A[M,K] @ Bt[N,K]^T + bias ----------------
// ROUND-18: REVERTED to the r8-verified 2-buffer/one-__syncthreads schedule.
// r9's 3-buffer counted-vmcnt variant regressed (74.3 -> 84.2us, MfmaUtil
// 29 -> 25): counted vmcnt + sched_barrier order-pinning defeats the
// compiler's scheduling in a 2-phase structure (guide regime-gate: T4 pays
// only inside the full 8-phase schedule). LDS XOR swizzle kept (verified:
// SQ_LDS_BANK_CONFLICT 6.29M -> 0, cost-free).
// MODE 0: A is y in [B,H,T,Dh] bf16; write fp32 C.
// MODE 1: A row-major [M,K] bf16; qkv scatter epilogue. V^T stored with the
//   key-chunk permutation for the attn zero-LDS-P path.
template <int MODE>
__global__ void __launch_bounds__(256)
gemm_bt_kernel(const u16* __restrict__ A, const u16* __restrict__ Bt,
               const float* __restrict__ bias, float* __restrict__ Cout,
               u16* __restrict__ qws, u16* __restrict__ kws, u16* __restrict__ vtws,
               int Mdim, int Ndim, int Kdim) {
    __shared__ u16 As[2][128 * 32];
    __shared__ u16 Bs[2][128 * 32];

    const int tid  = threadIdx.x;
    const int w    = tid >> 6;
    const int lane = tid & 63;
    const int l15  = lane & 15;
    const int quad = lane >> 4;
    const int wm   = (w & 1) * 64;
    const int wn   = (w >> 1) * 64;
    const int m0   = blockIdx.y * 128;
    const int n0   = blockIdx.x * 128;

    const int row0  = tid >> 2;              // 0..63
    const int row1  = row0 + 64;             // 64..127 ((row1>>1)&3 == (row0>>1)&3)
    // swizzled k-column for staging: c_phys = tid&3, fetch c_log = c_phys ^ ((row>>1)&3)
    const int colsw = (((tid & 3) ^ ((row0 >> 1) & 3))) << 3;   // u16 units

    f32x4 acc[4][4];
#pragma unroll
    for (int i = 0; i < 4; ++i)
#pragma unroll
        for (int j = 0; j < 4; ++j) acc[i][j] = (f32x4){0.f, 0.f, 0.f, 0.f};

    auto stageA = [&](int buf, int kc) {
        if (MODE == 0) {
            int kcc = kc + colsw, h = kcc >> 6, d = kcc & 63;
            int m = m0 + row0, b = m >> 11, t = m & 2047;
            GLL16(&A[(((size_t)(b * HH + h) * TT + t) * DH) + d], &As[buf][tid * 8]);
            m = m0 + row1; b = m >> 11; t = m & 2047;
            GLL16(&A[(((size_t)(b * HH + h) * TT + t) * DH) + d], &As[buf][(tid + 256) * 8]);
        } else {
            GLL16(&A[(size_t)(m0 + row0) * Kdim + kc + colsw], &As[buf][tid * 8]);
            GLL16(&A[(size_t)(m0 + row1) * Kdim + kc + colsw], &As[buf][(tid + 256) * 8]);
        }
    };

    // prologue: stage tile 0 into buffer 0
    stageA(0, 0);
    GLL16(&Bt[(size_t)(n0 + row0) * Kdim + colsw], &Bs[0][tid * 8]);
    GLL16(&Bt[(size_t)(n0 + row1) * Kdim + colsw], &Bs[0][(tid + 256) * 8]);

    // swizzled read column (constant per lane; row base bits are multiples of 16)
    const int csw = (quad ^ ((l15 >> 1) & 3)) * 8;

    const int nsteps = Kdim >> 5;
    for (int it = 0; it < nsteps; ++it) {
        const int buf = it & 1;
        __syncthreads();   // publishes tile `it` (drains its GLL16s — issued a full step ago)

        if (it + 1 < nsteps) {
            const int nbuf = buf ^ 1;
            const int kc = (it + 1) << 5;
            stageA(nbuf, kc);
            GLL16(&Bt[(size_t)(n0 + row0) * Kdim + kc + colsw], &Bs[nbuf][tid * 8]);
            GLL16(&Bt[(size_t)(n0 + row1) * Kdim + kc + colsw], &Bs[nbuf][(tid + 256) * 8]);
        }

        bf16x8 af[4], bfm[4];
#pragma unroll
        for (int mt = 0; mt < 4; ++mt)
            af[mt] = *(const bf16x8*)&As[buf][(wm + mt * 16 + l15) * 32 + csw];
#pragma unroll
        for (int nt = 0; nt < 4; ++nt)
            bfm[nt] = *(const bf16x8*)&Bs[buf][(wn + nt * 16 + l15) * 32 + csw];
#pragma unroll
        for (int mt = 0; mt < 4; ++mt)
#pragma unroll
            for (int nt = 0; nt < 4; ++nt)
                acc[mt][nt] = __builtin_amdgcn_mfma_f32_16x16x32_bf16(
                    af[mt], bfm[nt], acc[mt][nt], 0, 0, 0);
    }

    // epilogue: D row = quad*4+r, col = l15
#pragma unroll
    for (int mt = 0; mt < 4; ++mt) {
        int mrow_base = m0 + wm + mt * 16 + quad * 4;
#pragma unroll
        for (int nt = 0; nt < 4; ++nt) {
            int ncol = n0 + wn + nt * 16 + l15;
            float bv = bias[ncol];
            if (MODE == 0) {
#pragma unroll
                for (int r = 0; r < 4; ++r)
                    Cout[(size_t)(mrow_base + r) * Ndim + ncol] = acc[mt][nt][r] + bv;
            } else {
                int which = ncol >> 10, c = ncol & 1023;
                int h = c >> 6, d = c & 63;
                if (which == 2) {
                    // V^T: r spans 4 consecutive t -> packed store, with the
                    // key-permutation folded in: 4-key chunk [s3s2s1s0] -> [s3,s1,s0,s2]
                    int b = mrow_base >> 11, t = mrow_base & 2047;
                    int bh = b * HH + h;
                    int ch = (t >> 2) & 15;
                    int chp = (ch & 8) | (((ch >> 1) & 1) << 2) | ((ch & 1) << 1) | ((ch >> 2) & 1);
                    int tp = (t & ~63) | (chp << 2);
                    uint2 pv;
                    pv.x = cvt_pk_bf16(acc[mt][nt][0] + bv, acc[mt][nt][1] + bv);
                    pv.y = cvt_pk_bf16(acc[mt][nt][2] + bv, acc[mt][nt][3] + bv);
                    *(uint2*)&vtws[((size_t)bh * DH + d) * TT + tp] = pv;
                } else {
#pragma unroll
                    for (int r = 0; r < 4; ++r) {
                        int mrow = mrow_base + r;
                        int b = mrow >> 11, t = mrow & 2047;
                        int bh = b * HH + h;
                        float val = acc[mt][nt][r] + bv;
                        if (which == 0) {
                            // fold softmax scale and log2(e) into Q: 0.125*log2e
                            qws[((size_t)bh * TT + t) * DH + d] = f2bf(val * 0.18033688f);
                        } else {
                            kws[((size_t)bh * TT + t) * DH + d] = f2bf(val);
                        }
                    }
                }
            }
        }
    }
}

// ---------------- flash attention v11: zero-LDS P path (r7-verified) ----------------
// Chain per tile: barrier -> K/V b128 reads -> QK MFMA -> mask/exp2/cvt_pk ->
// PV MFMA. P never touches LDS (key-permutation trick; V^T pre-permuted by GEMM).
__global__ void __launch_bounds__(256, 3)
attn_kernel(const u16* __restrict__ qws, const u16* __restrict__ kws,
            const u16* __restrict__ vtws, u16* __restrict__ yws) {
    __shared__ u16 Ks[2][64 * 68];   // K tile  [key][d], stride 68 u16 (bank-balanced)
    __shared__ u16 Vs[2][64 * 68];   // V^T tile [d][key-permuted]

    const int tid  = threadIdx.x;
    const int w    = tid >> 6;       // 0..3
    const int lane = tid & 63;
    const int l15  = lane & 15;
    const int quad = lane >> 4;
    const int bh   = blockIdx.x;     // fast index: co-locates same-bh blocks per XCD
    const int qt   = 15 - blockIdx.y;   // heavy tiles first

    const u16* Kbase = kws + (size_t)bh * TT * DH;
    const u16* Vbase = vtws + (size_t)bh * DH * TT;

    // staging: 256 threads x 32B each for K and V (fully coalesced)
    const int srow  = tid >> 2;          // 0..63
    const int sc16  = (tid & 3) << 4;    // 0,16,32,48 (u16 units)

    bf16x8 aones;
#pragma unroll
    for (int i = 0; i < 8; ++i) aones[i] = __builtin_bit_cast(bf16_t, (u16)0x3F80);

    const int q0     = qt * 128;
    const int qr0    = q0 + w * 32;    // this wave's 32 queries
    const int ntiles = (q0 + 128) >> 6;

    // Q fragments as B-operand (lane=query, contiguous d); scale+log2e folded
    const u16* Qp = qws + ((size_t)bh * TT + qr0) * DH;
    bf16x8 bqa[2], bqb[2];
#pragma unroll
    for (int kk = 0; kk < 2; ++kk) {
        bqa[kk] = *(const bf16x8*)&Qp[l15 * DH + kk * 32 + quad * 8];
        bqb[kk] = *(const bf16x8*)&Qp[(16 + l15) * DH + kk * 32 + quad * 8];
    }

    f32x4 o[2][4], ol[2];
#pragma unroll
    for (int qg = 0; qg < 2; ++qg) {
#pragma unroll
        for (int dt = 0; dt < 4; ++dt) o[qg][dt] = (f32x4){0.f, 0.f, 0.f, 0.f};
        ol[qg] = (f32x4){0.f, 0.f, 0.f, 0.f};
    }

    // prologue: tile 0 -> regs -> LDS[0]; tile 1 -> regs
    uint4 pk0 = *(const uint4*)&Kbase[(size_t)srow * DH + sc16];
    uint4 pk1 = *(const uint4*)&Kbase[(size_t)srow * DH + sc16 + 8];
    uint4 pv0 = *(const uint4*)&Vbase[(size_t)srow * TT + sc16];
    uint4 pv1 = *(const uint4*)&Vbase[(size_t)srow * TT + sc16 + 8];
    *(uint4*)&Ks[0][srow * 68 + sc16]     = pk0;
    *(uint4*)&Ks[0][srow * 68 + sc16 + 8] = pk1;
    *(uint4*)&Vs[0][srow * 68 + sc16]     = pv0;
    *(uint4*)&Vs[0][srow * 68 + sc16 + 8] = pv1;
    if (ntiles > 1) {
        pk0 = *(const uint4*)&Kbase[(size_t)(64 + srow) * DH + sc16];
        pk1 = *(const uint4*)&Kbase[(size_t)(64 + srow) * DH + sc16 + 8];
        pv0 = *(const uint4*)&Vbase[(size_t)srow * TT + 64 + sc16];
        pv1 = *(const uint4*)&Vbase[(size_t)srow * TT + 64 + sc16 + 8];
    }

    for (int it = 0; it < ntiles; ++it) {
        const int buf = it & 1;
        __syncthreads();   // publishes tile `it`; frees buffer buf^1

        if (it + 1 < ntiles) {
            *(uint4*)&Ks[buf ^ 1][srow * 68 + sc16]     = pk0;
            *(uint4*)&Ks[buf ^ 1][srow * 68 + sc16 + 8] = pk1;
            *(uint4*)&Vs[buf ^ 1][srow * 68 + sc16]     = pv0;
            *(uint4*)&Vs[buf ^ 1][srow * 68 + sc16 + 8] = pv1;
            if (it + 2 < ntiles) {
                int jn = (it + 2) << 6;
                pk0 = *(const uint4*)&Kbase[(size_t)(jn + srow) * DH + sc16];
                pk1 = *(const uint4*)&Kbase[(size_t)(jn + srow) * DH + sc16 + 8];
                pv0 = *(const uint4*)&Vbase[(size_t)srow * TT + jn + sc16];
                pv1 = *(const uint4*)&Vbase[(size_t)srow * TT + jn + sc16 + 8];
            }
        }

        const int j0 = it << 6;
        if (j0 > qr0 + 31) continue;   // fully masked for this wave (both q-groups)

        // ---- K fragments ONCE, reused by both q-groups ----
        bf16x8 ak[8];
#pragma unroll
        for (int kk = 0; kk < 2; ++kk)
#pragma unroll
            for (int kt = 0; kt < 4; ++kt)
                ak[kk * 4 + kt] =
                    *(const bf16x8*)&Ks[buf][(kt * 16 + l15) * 68 + kk * 32 + quad * 8];

        // ---- V fragments (natural b128 reads; permutation lives in vtws) ----
        bf16x8 avr[8];
#pragma unroll
        for (int kk = 0; kk < 2; ++kk)
#pragma unroll
            for (int dt = 0; dt < 4; ++dt)
                avr[kk * 4 + dt] =
                    *(const bf16x8*)&Vs[buf][(dt * 16 + l15) * 68 + kk * 32 + quad * 8];

        // ---- S^T = K @ Q^T for both q-groups ----
        f32x4 sa[4], sb[4];
#pragma unroll
        for (int kt = 0; kt < 4; ++kt) {
            sa[kt] = (f32x4){0.f, 0.f, 0.f, 0.f};
            sb[kt] = (f32x4){0.f, 0.f, 0.f, 0.f};
        }
#pragma unroll
        for (int kk = 0; kk < 2; ++kk)
#pragma unroll
            for (int kt = 0; kt < 4; ++kt)
                sa[kt] = __builtin_amdgcn_mfma_f32_16x16x32_bf16(ak[kk * 4 + kt], bqa[kk], sa[kt], 0, 0, 0);
#pragma unroll
        for (int kk = 0; kk < 2; ++kk)
#pragma unroll
            for (int kt = 0; kt < 4; ++kt)
                sb[kt] = __builtin_amdgcn_mfma_f32_16x16x32_bf16(ak[kk * 4 + kt], bqb[kk], sb[kt], 0, 0, 0);

        // causal mask (diagonal region only): key > query -> -inf
        if (j0 + 63 > qr0) {
            int qy0 = qr0 + l15;
            int qy1 = qr0 + 16 + l15;
#pragma unroll
            for (int kt = 0; kt < 4; ++kt)
#pragma unroll
                for (int r = 0; r < 4; ++r) {
                    int key = j0 + kt * 16 + quad * 4 + r;
                    if (key > qy0) sa[kt][r] = -INFINITY;
                    if (key > qy1) sb[kt][r] = -INFINITY;
                }
        }

        // ---- max-free softmax: p = exp2(s) ----
#pragma unroll
        for (int kt = 0; kt < 4; ++kt)
#pragma unroll
            for (int r = 0; r < 4; ++r) {
                sa[kt][r] = __builtin_amdgcn_exp2f(sa[kt][r]);
                sb[kt][r] = __builtin_amdgcn_exp2f(sb[kt][r]);
            }

        // ---- P -> PV B-operand DIRECTLY in-register: bp(kk) = pack(s[2kk],s[2kk+1]).
        // Slot->key bijection is matched by the permuted V^T layout. No LDS. ----
        uint4 ua0, ua1, ub0, ub1;
        ua0.x = cvt_pk_bf16(sa[0][0], sa[0][1]);
        ua0.y = cvt_pk_bf16(sa[0][2], sa[0][3]);
        ua0.z = cvt_pk_bf16(sa[1][0], sa[1][1]);
        ua0.w = cvt_pk_bf16(sa[1][2], sa[1][3]);
        ua1.x = cvt_pk_bf16(sa[2][0], sa[2][1]);
        ua1.y = cvt_pk_bf16(sa[2][2], sa[2][3]);
        ua1.z = cvt_pk_bf16(sa[3][0], sa[3][1]);
        ua1.w = cvt_pk_bf16(sa[3][2], sa[3][3]);
        ub0.x = cvt_pk_bf16(sb[0][0], sb[0][1]);
        ub0.y = cvt_pk_bf16(sb[0][2], sb[0][3]);
        ub0.z = cvt_pk_bf16(sb[1][0], sb[1][1]);
        ub0.w = cvt_pk_bf16(sb[1][2], sb[1][3]);
        ub1.x = cvt_pk_bf16(sb[2][0], sb[2][1]);
        ub1.y = cvt_pk_bf16(sb[2][2], sb[2][3]);
        ub1.z = cvt_pk_bf16(sb[3][0], sb[3][1]);
        ub1.w = cvt_pk_bf16(sb[3][2], sb[3][3]);
        bf16x8 bpa0 = __builtin_bit_cast(bf16x8, ua0);
        bf16x8 bpa1 = __builtin_bit_cast(bf16x8, ua1);
        bf16x8 bpb0 = __builtin_bit_cast(bf16x8, ub0);
        bf16x8 bpb1 = __builtin_bit_cast(bf16x8, ub1);

        // ---- O^T += V^T @ P^T ; l += ones @ P^T (fused row-sum) ----
#pragma unroll
        for (int dt = 0; dt < 4; ++dt)
            o[0][dt] = __builtin_amdgcn_mfma_f32_16x16x32_bf16(avr[dt], bpa0, o[0][dt], 0, 0, 0);
        ol[0] = __builtin_amdgcn_mfma_f32_16x16x32_bf16(aones, bpa0, ol[0], 0, 0, 0);
#pragma unroll
        for (int dt = 0; dt < 4; ++dt)
            o[0][dt] = __builtin_amdgcn_mfma_f32_16x16x32_bf16(avr[4 + dt], bpa1, o[0][dt], 0, 0, 0);
        ol[0] = __builtin_amdgcn_mfma_f32_16x16x32_bf16(aones, bpa1, ol[0], 0, 0, 0);
#pragma unroll
        for (int dt = 0; dt < 4; ++dt)
            o[1][dt] = __builtin_amdgcn_mfma_f32_16x16x32_bf16(avr[dt], bpb0, o[1][dt], 0, 0, 0);
        ol[1] = __builtin_amdgcn_mfma_f32_16x16x32_bf16(aones, bpb0, ol[1], 0, 0, 0);
#pragma unroll
        for (int dt = 0; dt < 4; ++dt)
            o[1][dt] = __builtin_amdgcn_mfma_f32_16x16x32_bf16(avr[4 + dt], bpb1, o[1][dt], 0, 0, 0);
        ol[1] = __builtin_amdgcn_mfma_f32_16x16x32_bf16(aones, bpb1, ol[1], 0, 0, 0);
    }

    // ---- normalize + store O^T to y[B,H,T,Dh] (coalesced) ----
#pragma unroll
    for (int qg = 0; qg < 2; ++qg) {
        float rinv = __builtin_amdgcn_rcpf(ol[qg][0]);   // l[query]; ~1ulp ok at bf16 out
        int t = qr0 + qg * 16 + l15;
#pragma unroll
        for (int dt = 0; dt < 4; ++dt) {
            uint2 yv;
            yv.x = cvt_pk_bf16(o[qg][dt][0] * rinv, o[qg][dt][1] * rinv);
            yv.y = cvt_pk_bf16(o[qg][dt][2] * rinv, o[qg][dt][3] * rinv);
            *(uint2*)&yws[((size_t)bh * TT + t) * DH + dt * 16 + quad * 4] = yv;
        }
    }
}

// ---------------- launch ----------------

extern "C" void kernel_launch(void* const* d_in, const int* in_sizes, int n_in,
                              void* d_out, int out_size, void* d_ws, size_t ws_size,
                              hipStream_t stream) {
    const float* x     = (const float*)d_in[0];
    const float* W_qkv = (const float*)d_in[1];
    const float* b_qkv = (const float*)d_in[2];
    const float* W_out = (const float*)d_in[3];
    const float* b_out = (const float*)d_in[4];
    float* out = (float*)d_out;

    char* ws = (char*)d_ws;
    u16* xb   = (u16*)ws; ws += (size_t)MM * CC * 2;       // x bf16        16 MB
    u16* wqt  = (u16*)ws; ws += (size_t)3 * CC * CC * 2;   // W_qkv^T bf16   6 MB
    u16* wot  = (u16*)ws; ws += (size_t)CC * CC * 2;       // W_out^T bf16   2 MB
    u16* qws  = (u16*)ws; ws += (size_t)MM * CC * 2;       // Q [B,H,T,Dh]  16 MB
    u16* kws  = (u16*)ws; ws += (size_t)MM * CC * 2;       // K [B,H,T,Dh]  16 MB
    u16* vtws = (u16*)ws; ws += (size_t)MM * CC * 2;       // V^T [B,H,Dh,T] (key-permuted) 16 MB
    u16* yws  = (u16*)ws; ws += (size_t)MM * CC * 2;       // y [B,H,T,Dh]  16 MB

    // 4 launches (was 6): fused prep -> gemm1 -> attn -> gemm2
    prep_kernel<<<8192 + 3072 + 1024, 256, 0, stream>>>(x, xb, W_qkv, wqt, W_out, wot);

    gemm_bt_kernel<1><<<dim3(24, 64), 256, 0, stream>>>(
        xb, wqt, b_qkv, nullptr, qws, kws, vtws, MM, 3 * CC, CC);

    attn_kernel<<<dim3(BB * HH, 16), 256, 0, stream>>>(qws, kws, vtws, yws);

    gemm_bt_kernel<0><<<dim3(8, 64), 256, 0, stream>>>(
        yws, wot, b_out, out, nullptr, nullptr, nullptr, MM, CC, CC);
}

// Round 11
// 232.888 us; speedup vs baseline: 1.0205x; 1.0036x over previous
//
#include <hip/hip_runtime.h>
#include <cstdint>
#include <math.h>

#define TT 2048
#define CC 1024
#define HH 16
#define DH 64
#define BB 4
#define MM 8192   // B*T

typedef unsigned short u16;
typedef __bf16 bf16_t;
typedef bf16_t bf16x8 __attribute__((ext_vector_type(8)));
typedef float f32x4 __attribute__((ext_vector_type(4)));

// fp32 -> bf16 round-to-nearest-even (scalar)
static __device__ inline u16 f2bf(float f) {
    unsigned int u = __builtin_bit_cast(unsigned int, f);
    unsigned int lsb = (u >> 16) & 1u;
    u += 0x7fffu + lsb;
    return (u16)(u >> 16);
}

// packed 2xfp32 -> 2xbf16 (gfx950 v_cvt_pk_bf16_f32, RNE)
static __device__ inline unsigned int cvt_pk_bf16(float a, float b) {
    unsigned int r;
    asm volatile("v_cvt_pk_bf16_f32 %0, %1, %2" : "=v"(r) : "v"(a), "v"(b));
    return r;
}

// async 16B global->LDS (LDS dest wave-uniform + lane*16B)
#define GLL16(gptr, lptr)                                                            \
    __builtin_amdgcn_global_load_lds(                                                \
        (__attribute__((address_space(1))) void*)(gptr),                             \
        (__attribute__((address_space(3))) void*)(lptr), 16, 0, 0)

// ---------------- fused prep kernel (r18-verified) ----------------
__global__ void __launch_bounds__(256)
prep_kernel(const float* __restrict__ x, u16* __restrict__ xb,
            const float* __restrict__ Wq, u16* __restrict__ wqt,
            const float* __restrict__ Wo, u16* __restrict__ wot) {
    const int bid = blockIdx.x;
    if (bid < 8192) {                       // cast x
        int i = bid * 256 + threadIdx.x;
        float4 v = ((const float4*)x)[i];
        uint2 o;
        o.x = cvt_pk_bf16(v.x, v.y);
        o.y = cvt_pk_bf16(v.z, v.w);
        ((uint2*)xb)[i] = o;
        return;
    }
    __shared__ u16 tile[32 * 34];
    const float* W; u16* Wt; int N, n0, k0;
    if (bid < 8192 + 3072) {                // W_qkv
        int idx = bid - 8192;
        W = Wq; Wt = wqt; N = 3 * CC;
        n0 = (idx % 96) * 32; k0 = (idx / 96) * 32;
    } else {                                // W_out
        int idx = bid - 11264;
        W = Wo; Wt = wot; N = CC;
        n0 = (idx % 32) * 32; k0 = (idx / 32) * 32;
    }
    const int tx = threadIdx.x & 31;
    const int ty = threadIdx.x >> 5;
#pragma unroll
    for (int i = 0; i < 4; ++i) {
        int k = ty + i * 8;
        tile[tx * 34 + k] = f2bf(W[(size_t)(k0 + k) * N + n0 + tx]);
    }
    __syncthreads();
    const int tx2 = threadIdx.x & 15;
    const int ty2 = threadIdx.x >> 4;
#pragma unroll
    for (int i = 0; i < 2; ++i) {
        int r = ty2 + i * 16;
        *(unsigned int*)&Wt[(size_t)(n0 + r) * CC + k0 + 2 * tx2] =
            *(unsigned int*)&tile[r * 34 + 2 * tx2];
    }
}

// ---------------- GEMM1: 8-phase 256x256 (ROUND-19) ----------------
// r10 showed gemm1 pinned at 682 TF = the measured 2-phase ceiling (m230/248);
// path past it is the 8-phase counted-vmcnt schedule (m198 1167 TF even with
// linear LDS). Self-derived race-free variant, verified by region analysis:
//  * 512 thr / 8 waves (2M x 4N); per-wave output 128x64; BK=64; K=1024 -> 16 tiles.
//  * LDS 128KB: A[buf][kh][256x32 u16], B same (+32768 u16). XOR swizzle
//    (col-group ^ ((row>>1)&3)) on BOTH stage-source and read (r8-verified form).
//  * Per tile, 4 phases (kk = q>>1, m-half = q&1, 16 MFMA each). Staging of
//    tile t+1 -> buf^1 (fully consumed one tile ago -> always write-safe),
//    one half-tile (2 GLL16/thread) per phase in deadline order
//    {A-k0, B-k0, A-k32, B-k32}.
//  * Sync: barriers ONLY at q=0,2 (rendezvous so other waves' GLL16s landed);
//    vmcnt(4) at q=0 (prev-tile A-k0+B-k0 drained) and q=2 (A-k32+B-k32);
//    NEVER vmcnt(0) in steady state. sched_barrier(0) at both sync points
//    keeps the issue-region ordering the vmcnt count relies on.
//  * Epilogue = r7-verified MODE-1 scatter (Q scale-folded, K, V^T key-permuted)
//    with 8-wave index mapping.
__global__ void __launch_bounds__(512, 2)
gemm1_kernel(const u16* __restrict__ A, const u16* __restrict__ Bt,
             const float* __restrict__ bias,
             u16* __restrict__ qws, u16* __restrict__ kws, u16* __restrict__ vtws) {
    __shared__ u16 lds[65536];   // 128 KB

    const int tid  = threadIdx.x;          // 0..511
    const int w    = tid >> 6;             // 0..7
    const int lane = tid & 63;
    const int l15  = lane & 15;
    const int quad = lane >> 4;
    const int wm2  = w >> 2;               // 0..1: row half (128)
    const int wn4  = w & 3;                // 0..3: col quarter (64)
    const int m0   = blockIdx.y * 256;
    const int n0   = blockIdx.x * 256;

    const int csw  = (quad ^ ((l15 >> 1) & 3)) * 8;  // swizzled read col (u16)

    // staging: chunk c = j*512+tid; row = j*128 + (tid>>2); phys group = tid&3
    const int srow = tid >> 2;             // 0..127 (+ j*128)
    const int sgp  = tid & 3;
    const int sgl  = (sgp ^ ((srow >> 1) & 3)) * 8;  // logical col fetched (u16)

    f32x4 acc[8][4];
#pragma unroll
    for (int i = 0; i < 8; ++i)
#pragma unroll
        for (int j = 0; j < 4; ++j) acc[i][j] = (f32x4){0.f, 0.f, 0.f, 0.f};

    auto stA = [&](int buf, int kh, int kt) {
#pragma unroll
        for (int j = 0; j < 2; ++j) {
            int row = j * 128 + srow;
            GLL16(&A[(size_t)(m0 + row) * CC + kt * 64 + kh * 32 + sgl],
                  &lds[(size_t)(buf * 2 + kh) * 8192 + (j * 512 + tid) * 8]);
        }
    };
    auto stB = [&](int buf, int kh, int kt) {
#pragma unroll
        for (int j = 0; j < 2; ++j) {
            int row = j * 128 + srow;
            GLL16(&Bt[(size_t)(n0 + row) * CC + kt * 64 + kh * 32 + sgl],
                  &lds[32768 + (size_t)(buf * 2 + kh) * 8192 + (j * 512 + tid) * 8]);
        }
    };

    const int ntiles = CC / 64;            // 16
    // prologue: tile 0 in deadline order (A-k0, B-k0 | A-k32, B-k32)
    stA(0, 0, 0); stB(0, 0, 0);
    __builtin_amdgcn_sched_barrier(0);     // keep the two half-tile pairs ordered
    stA(0, 1, 0); stB(0, 1, 0);

    for (int t = 0; t < ntiles; ++t) {
        const int buf  = t & 1;
        const int nbuf = buf ^ 1;
        const bool more = (t + 1 < ntiles);

#pragma unroll
        for (int q = 0; q < 4; ++q) {
            const int kk = q >> 1;
            const int mq = q & 1;

            if (q == 0) {
                // prev 4 phases staged this tile's 8 loads; oldest 4 = {A-k0,B-k0}
                asm volatile("s_waitcnt vmcnt(4)" ::: "memory");
                __builtin_amdgcn_s_barrier();
                __builtin_amdgcn_sched_barrier(0);
            } else if (q == 2) {
                // drain this tile's {A-k32,B-k32} (staged at prev tile q2,q3)
                if (more) asm volatile("s_waitcnt vmcnt(4)" ::: "memory");
                else      asm volatile("s_waitcnt vmcnt(0)" ::: "memory");
                __builtin_amdgcn_s_barrier();
                __builtin_amdgcn_sched_barrier(0);
            }

            if (more) {
                if      (q == 0) stA(nbuf, 0, t + 1);
                else if (q == 1) stB(nbuf, 0, t + 1);
                else if (q == 2) stA(nbuf, 1, t + 1);
                else             stB(nbuf, 1, t + 1);
            }

            bf16x8 af[4], bfm[4];
            const int abase = (buf * 2 + kk) * 8192;
            const int bbase = 32768 + (buf * 2 + kk) * 8192;
#pragma unroll
            for (int i = 0; i < 4; ++i)
                af[i] = *(const bf16x8*)&lds[abase + (wm2 * 128 + (mq * 4 + i) * 16 + l15) * 32 + csw];
#pragma unroll
            for (int nt = 0; nt < 4; ++nt)
                bfm[nt] = *(const bf16x8*)&lds[bbase + (wn4 * 64 + nt * 16 + l15) * 32 + csw];

            __builtin_amdgcn_s_setprio(1);
#pragma unroll
            for (int i = 0; i < 4; ++i)
#pragma unroll
                for (int nt = 0; nt < 4; ++nt)
                    acc[mq * 4 + i][nt] = __builtin_amdgcn_mfma_f32_16x16x32_bf16(
                        af[i], bfm[nt], acc[mq * 4 + i][nt], 0, 0, 0);
            __builtin_amdgcn_s_setprio(0);
        }
    }

    // epilogue: qkv scatter (Q scale-folded, K, V^T key-permuted)
#pragma unroll
    for (int mt = 0; mt < 8; ++mt) {
        int mrow_base = m0 + wm2 * 128 + mt * 16 + quad * 4;
#pragma unroll
        for (int nt = 0; nt < 4; ++nt) {
            int ncol = n0 + wn4 * 64 + nt * 16 + l15;
            float bv = bias[ncol];
            int which = ncol >> 10, c = ncol & 1023;
            int h = c >> 6, d = c & 63;
            if (which == 2) {
                int b = mrow_base >> 11, t = mrow_base & 2047;
                int bh = b * HH + h;
                int ch = (t >> 2) & 15;
                int chp = (ch & 8) | (((ch >> 1) & 1) << 2) | ((ch & 1) << 1) | ((ch >> 2) & 1);
                int tp = (t & ~63) | (chp << 2);
                uint2 pv;
                pv.x = cvt_pk_bf16(acc[mt][nt][0] + bv, acc[mt][nt][1] + bv);
                pv.y = cvt_pk_bf16(acc[mt][nt][2] + bv, acc[mt][nt][3] + bv);
                *(uint2*)&vtws[((size_t)bh * DH + d) * TT + tp] = pv;
            } else {
#pragma unroll
                for (int r = 0; r < 4; ++r) {
                    int mrow = mrow_base + r;
                    int b = mrow >> 11, t = mrow & 2047;
                    int bh = b * HH + h;
                    float val = acc[mt][nt][r] + bv;
                    if (which == 0) {
                        qws[((size_t)bh * TT + t) * DH + d] = f2bf(val * 0.18033688f);
                    } else {
                        kws[((size_t)bh * TT + t) * DH + d] = f2bf(val);
                    }
                }
            }
        }
    }
}

// ---------------- GEMM (2-phase 128x128, r8-verified) — used for gemm2 ----------------
template <int MODE>
__global__ void __launch_bounds__(256)
gemm_bt_kernel(const u16* __restrict__ A, const u16* __restrict__ Bt,
               const float* __restrict__ bias, float* __restrict__ Cout,
               u16* __restrict__ qws, u16* __restrict__ kws, u16* __restrict__ vtws,
               int Mdim, int Ndim, int Kdim) {
    __shared__ u16 As[2][128 * 32];
    __shared__ u16 Bs[2][128 * 32];

    const int tid  = threadIdx.x;
    const int w    = tid >> 6;
    const int lane = tid & 63;
    const int l15  = lane & 15;
    const int quad = lane >> 4;
    const int wm   = (w & 1) * 64;
    const int wn   = (w >> 1) * 64;
    const int m0   = blockIdx.y * 128;
    const int n0   = blockIdx.x * 128;

    const int row0  = tid >> 2;
    const int row1  = row0 + 64;
    const int colsw = (((tid & 3) ^ ((row0 >> 1) & 3))) << 3;

    f32x4 acc[4][4];
#pragma unroll
    for (int i = 0; i < 4; ++i)
#pragma unroll
        for (int j = 0; j < 4; ++j) acc[i][j] = (f32x4){0.f, 0.f, 0.f, 0.f};

    auto stageA = [&](int buf, int kc) {
        if (MODE == 0) {
            int kcc = kc + colsw, h = kcc >> 6, d = kcc & 63;
            int m = m0 + row0, b = m >> 11, t = m & 2047;
            GLL16(&A[(((size_t)(b * HH + h) * TT + t) * DH) + d], &As[buf][tid * 8]);
            m = m0 + row1; b = m >> 11; t = m & 2047;
            GLL16(&A[(((size_t)(b * HH + h) * TT + t) * DH) + d], &As[buf][(tid + 256) * 8]);
        } else {
            GLL16(&A[(size_t)(m0 + row0) * Kdim + kc + colsw], &As[buf][tid * 8]);
            GLL16(&A[(size_t)(m0 + row1) * Kdim + kc + colsw], &As[buf][(tid + 256) * 8]);
        }
    };

    stageA(0, 0);
    GLL16(&Bt[(size_t)(n0 + row0) * Kdim + colsw], &Bs[0][tid * 8]);
    GLL16(&Bt[(size_t)(n0 + row1) * Kdim + colsw], &Bs[0][(tid + 256) * 8]);

    const int csw = (quad ^ ((l15 >> 1) & 3)) * 8;

    const int nsteps = Kdim >> 5;
    for (int it = 0; it < nsteps; ++it) {
        const int buf = it & 1;
        __syncthreads();

        if (it + 1 < nsteps) {
            const int nbuf = buf ^ 1;
            const int kc = (it + 1) << 5;
            stageA(nbuf, kc);
            GLL16(&Bt[(size_t)(n0 + row0) * Kdim + kc + colsw], &Bs[nbuf][tid * 8]);
            GLL16(&Bt[(size_t)(n0 + row1) * Kdim + kc + colsw], &Bs[nbuf][(tid + 256) * 8]);
        }

        bf16x8 af[4], bfm[4];
#pragma unroll
        for (int mt = 0; mt < 4; ++mt)
            af[mt] = *(const bf16x8*)&As[buf][(wm + mt * 16 + l15) * 32 + csw];
#pragma unroll
        for (int nt = 0; nt < 4; ++nt)
            bfm[nt] = *(const bf16x8*)&Bs[buf][(wn + nt * 16 + l15) * 32 + csw];
#pragma unroll
        for (int mt = 0; mt < 4; ++mt)
#pragma unroll
            for (int nt = 0; nt < 4; ++nt)
                acc[mt][nt] = __builtin_amdgcn_mfma_f32_16x16x32_bf16(
                    af[mt], bfm[nt], acc[mt][nt], 0, 0, 0);
    }

#pragma unroll
    for (int mt = 0; mt < 4; ++mt) {
        int mrow_base = m0 + wm + mt * 16 + quad * 4;
#pragma unroll
        for (int nt = 0; nt < 4; ++nt) {
            int ncol = n0 + wn + nt * 16 + l15;
            float bv = bias[ncol];
            if (MODE == 0) {
#pragma unroll
                for (int r = 0; r < 4; ++r)
                    Cout[(size_t)(mrow_base + r) * Ndim + ncol] = acc[mt][nt][r] + bv;
            } else {
                int which = ncol >> 10, c = ncol & 1023;
                int h = c >> 6, d = c & 63;
                if (which == 2) {
                    int b = mrow_base >> 11, t = mrow_base & 2047;
                    int bh = b * HH + h;
                    int ch = (t >> 2) & 15;
                    int chp = (ch & 8) | (((ch >> 1) & 1) << 2) | ((ch & 1) << 1) | ((ch >> 2) & 1);
                    int tp = (t & ~63) | (chp << 2);
                    uint2 pv;
                    pv.x = cvt_pk_bf16(acc[mt][nt][0] + bv, acc[mt][nt][1] + bv);
                    pv.y = cvt_pk_bf16(acc[mt][nt][2] + bv, acc[mt][nt][3] + bv);
                    *(uint2*)&vtws[((size_t)bh * DH + d) * TT + tp] = pv;
                } else {
#pragma unroll
                    for (int r = 0; r < 4; ++r) {
                        int mrow = mrow_base + r;
                        int b = mrow >> 11, t = mrow & 2047;
                        int bh = b * HH + h;
                        float val = acc[mt][nt][r] + bv;
                        if (which == 0) {
                            qws[((size_t)bh * TT + t) * DH + d] = f2bf(val * 0.18033688f);
                        } else {
                            kws[((size_t)bh * TT + t) * DH + d] = f2bf(val);
                        }
                    }
                }
            }
        }
    }
}

// ---------------- flash attention v11: zero-LDS P path (r7-verified) ----------------
__global__ void __launch_bounds__(256, 3)
attn_kernel(const u16* __restrict__ qws, const u16* __restrict__ kws,
            const u16* __restrict__ vtws, u16* __restrict__ yws) {
    __shared__ u16 Ks[2][64 * 68];
    __shared__ u16 Vs[2][64 * 68];

    const int tid  = threadIdx.x;
    const int w    = tid >> 6;
    const int lane = tid & 63;
    const int l15  = lane & 15;
    const int quad = lane >> 4;
    const int bh   = blockIdx.x;
    const int qt   = 15 - blockIdx.y;

    const u16* Kbase = kws + (size_t)bh * TT * DH;
    const u16* Vbase = vtws + (size_t)bh * DH * TT;

    const int srow  = tid >> 2;
    const int sc16  = (tid & 3) << 4;

    bf16x8 aones;
#pragma unroll
    for (int i = 0; i < 8; ++i) aones[i] = __builtin_bit_cast(bf16_t, (u16)0x3F80);

    const int q0     = qt * 128;
    const int qr0    = q0 + w * 32;
    const int ntiles = (q0 + 128) >> 6;

    const u16* Qp = qws + ((size_t)bh * TT + qr0) * DH;
    bf16x8 bqa[2], bqb[2];
#pragma unroll
    for (int kk = 0; kk < 2; ++kk) {
        bqa[kk] = *(const bf16x8*)&Qp[l15 * DH + kk * 32 + quad * 8];
        bqb[kk] = *(const bf16x8*)&Qp[(16 + l15) * DH + kk * 32 + quad * 8];
    }

    f32x4 o[2][4], ol[2];
#pragma unroll
    for (int qg = 0; qg < 2; ++qg) {
#pragma unroll
        for (int dt = 0; dt < 4; ++dt) o[qg][dt] = (f32x4){0.f, 0.f, 0.f, 0.f};
        ol[qg] = (f32x4){0.f, 0.f, 0.f, 0.f};
    }

    uint4 pk0 = *(const uint4*)&Kbase[(size_t)srow * DH + sc16];
    uint4 pk1 = *(const uint4*)&Kbase[(size_t)srow * DH + sc16 + 8];
    uint4 pv0 = *(const uint4*)&Vbase[(size_t)srow * TT + sc16];
    uint4 pv1 = *(const uint4*)&Vbase[(size_t)srow * TT + sc16 + 8];
    *(uint4*)&Ks[0][srow * 68 + sc16]     = pk0;
    *(uint4*)&Ks[0][srow * 68 + sc16 + 8] = pk1;
    *(uint4*)&Vs[0][srow * 68 + sc16]     = pv0;
    *(uint4*)&Vs[0][srow * 68 + sc16 + 8] = pv1;
    if (ntiles > 1) {
        pk0 = *(const uint4*)&Kbase[(size_t)(64 + srow) * DH + sc16];
        pk1 = *(const uint4*)&Kbase[(size_t)(64 + srow) * DH + sc16 + 8];
        pv0 = *(const uint4*)&Vbase[(size_t)srow * TT + 64 + sc16];
        pv1 = *(const uint4*)&Vbase[(size_t)srow * TT + 64 + sc16 + 8];
    }

    for (int it = 0; it < ntiles; ++it) {
        const int buf = it & 1;
        __syncthreads();

        if (it + 1 < ntiles) {
            *(uint4*)&Ks[buf ^ 1][srow * 68 + sc16]     = pk0;
            *(uint4*)&Ks[buf ^ 1][srow * 68 + sc16 + 8] = pk1;
            *(uint4*)&Vs[buf ^ 1][srow * 68 + sc16]     = pv0;
            *(uint4*)&Vs[buf ^ 1][srow * 68 + sc16 + 8] = pv1;
            if (it + 2 < ntiles) {
                int jn = (it + 2) << 6;
                pk0 = *(const uint4*)&Kbase[(size_t)(jn + srow) * DH + sc16];
                pk1 = *(const uint4*)&Kbase[(size_t)(jn + srow) * DH + sc16 + 8];
                pv0 = *(const uint4*)&Vbase[(size_t)srow * TT + jn + sc16];
                pv1 = *(const uint4*)&Vbase[(size_t)srow * TT + jn + sc16 + 8];
            }
        }

        const int j0 = it << 6;
        if (j0 > qr0 + 31) continue;

        bf16x8 ak[8];
#pragma unroll
        for (int kk = 0; kk < 2; ++kk)
#pragma unroll
            for (int kt = 0; kt < 4; ++kt)
                ak[kk * 4 + kt] =
                    *(const bf16x8*)&Ks[buf][(kt * 16 + l15) * 68 + kk * 32 + quad * 8];

        bf16x8 avr[8];
#pragma unroll
        for (int kk = 0; kk < 2; ++kk)
#pragma unroll
            for (int dt = 0; dt < 4; ++dt)
                avr[kk * 4 + dt] =
                    *(const bf16x8*)&Vs[buf][(dt * 16 + l15) * 68 + kk * 32 + quad * 8];

        f32x4 sa[4], sb[4];
#pragma unroll
        for (int kt = 0; kt < 4; ++kt) {
            sa[kt] = (f32x4){0.f, 0.f, 0.f, 0.f};
            sb[kt] = (f32x4){0.f, 0.f, 0.f, 0.f};
        }
#pragma unroll
        for (int kk = 0; kk < 2; ++kk)
#pragma unroll
            for (int kt = 0; kt < 4; ++kt)
                sa[kt] = __builtin_amdgcn_mfma_f32_16x16x32_bf16(ak[kk * 4 + kt], bqa[kk], sa[kt], 0, 0, 0);
#pragma unroll
        for (int kk = 0; kk < 2; ++kk)
#pragma unroll
            for (int kt = 0; kt < 4; ++kt)
                sb[kt] = __builtin_amdgcn_mfma_f32_16x16x32_bf16(ak[kk * 4 + kt], bqb[kk], sb[kt], 0, 0, 0);

        if (j0 + 63 > qr0) {
            int qy0 = qr0 + l15;
            int qy1 = qr0 + 16 + l15;
#pragma unroll
            for (int kt = 0; kt < 4; ++kt)
#pragma unroll
                for (int r = 0; r < 4; ++r) {
                    int key = j0 + kt * 16 + quad * 4 + r;
                    if (key > qy0) sa[kt][r] = -INFINITY;
                    if (key > qy1) sb[kt][r] = -INFINITY;
                }
        }

#pragma unroll
        for (int kt = 0; kt < 4; ++kt)
#pragma unroll
            for (int r = 0; r < 4; ++r) {
                sa[kt][r] = __builtin_amdgcn_exp2f(sa[kt][r]);
                sb[kt][r] = __builtin_amdgcn_exp2f(sb[kt][r]);
            }

        uint4 ua0, ua1, ub0, ub1;
        ua0.x = cvt_pk_bf16(sa[0][0], sa[0][1]);
        ua0.y = cvt_pk_bf16(sa[0][2], sa[0][3]);
        ua0.z = cvt_pk_bf16(sa[1][0], sa[1][1]);
        ua0.w = cvt_pk_bf16(sa[1][2], sa[1][3]);
        ua1.x = cvt_pk_bf16(sa[2][0], sa[2][1]);
        ua1.y = cvt_pk_bf16(sa[2][2], sa[2][3]);
        ua1.z = cvt_pk_bf16(sa[3][0], sa[3][1]);
        ua1.w = cvt_pk_bf16(sa[3][2], sa[3][3]);
        ub0.x = cvt_pk_bf16(sb[0][0], sb[0][1]);
        ub0.y = cvt_pk_bf16(sb[0][2], sb[0][3]);
        ub0.z = cvt_pk_bf16(sb[1][0], sb[1][1]);
        ub0.w = cvt_pk_bf16(sb[1][2], sb[1][3]);
        ub1.x = cvt_pk_bf16(sb[2][0], sb[2][1]);
        ub1.y = cvt_pk_bf16(sb[2][2], sb[2][3]);
        ub1.z = cvt_pk_bf16(sb[3][0], sb[3][1]);
        ub1.w = cvt_pk_bf16(sb[3][2], sb[3][3]);
        bf16x8 bpa0 = __builtin_bit_cast(bf16x8, ua0);
        bf16x8 bpa1 = __builtin_bit_cast(bf16x8, ua1);
        bf16x8 bpb0 = __builtin_bit_cast(bf16x8, ub0);
        bf16x8 bpb1 = __builtin_bit_cast(bf16x8, ub1);

#pragma unroll
        for (int dt = 0; dt < 4; ++dt)
            o[0][dt] = __builtin_amdgcn_mfma_f32_16x16x32_bf16(avr[dt], bpa0, o[0][dt], 0, 0, 0);
        ol[0] = __builtin_amdgcn_mfma_f32_16x16x32_bf16(aones, bpa0, ol[0], 0, 0, 0);
#pragma unroll
        for (int dt = 0; dt < 4; ++dt)
            o[0][dt] = __builtin_amdgcn_mfma_f32_16x16x32_bf16(avr[4 + dt], bpa1, o[0][dt], 0, 0, 0);
        ol[0] = __builtin_amdgcn_mfma_f32_16x16x32_bf16(aones, bpa1, ol[0], 0, 0, 0);
#pragma unroll
        for (int dt = 0; dt < 4; ++dt)
            o[1][dt] = __builtin_amdgcn_mfma_f32_16x16x32_bf16(avr[dt], bpb0, o[1][dt], 0, 0, 0);
        ol[1] = __builtin_amdgcn_mfma_f32_16x16x32_bf16(aones, bpb0, ol[1], 0, 0, 0);
#pragma unroll
        for (int dt = 0; dt < 4; ++dt)
            o[1][dt] = __builtin_amdgcn_mfma_f32_16x16x32_bf16(avr[4 + dt], bpb1, o[1][dt], 0, 0, 0);
        ol[1] = __builtin_amdgcn_mfma_f32_16x16x32_bf16(aones, bpb1, ol[1], 0, 0, 0);
    }

#pragma unroll
    for (int qg = 0; qg < 2; ++qg) {
        float rinv = __builtin_amdgcn_rcpf(ol[qg][0]);
        int t = qr0 + qg * 16 + l15;
#pragma unroll
        for (int dt = 0; dt < 4; ++dt) {
            uint2 yv;
            yv.x = cvt_pk_bf16(o[qg][dt][0] * rinv, o[qg][dt][1] * rinv);
            yv.y = cvt_pk_bf16(o[qg][dt][2] * rinv, o[qg][dt][3] * rinv);
            *(uint2*)&yws[((size_t)bh * TT + t) * DH + dt * 16 + quad * 4] = yv;
        }
    }
}

// ---------------- launch ----------------

extern "C" void kernel_launch(void* const* d_in, const int* in_sizes, int n_in,
                              void* d_out, int out_size, void* d_ws, size_t ws_size,
                              hipStream_t stream) {
    const float* x     = (const float*)d_in[0];
    const float* W_qkv = (const float*)d_in[1];
    const float* b_qkv = (const float*)d_in[2];
    const float* W_out = (const float*)d_in[3];
    const float* b_out = (const float*)d_in[4];
    float* out = (float*)d_out;

    char* ws = (char*)d_ws;
    u16* xb   = (u16*)ws; ws += (size_t)MM * CC * 2;       // x bf16        16 MB
    u16* wqt  = (u16*)ws; ws += (size_t)3 * CC * CC * 2;   // W_qkv^T bf16   6 MB
    u16* wot  = (u16*)ws; ws += (size_t)CC * CC * 2;       // W_out^T bf16   2 MB
    u16* qws  = (u16*)ws; ws += (size_t)MM * CC * 2;       // Q [B,H,T,Dh]  16 MB
    u16* kws  = (u16*)ws; ws += (size_t)MM * CC * 2;       // K [B,H,T,Dh]  16 MB
    u16* vtws = (u16*)ws; ws += (size_t)MM * CC * 2;       // V^T (key-permuted) 16 MB
    u16* yws  = (u16*)ws; ws += (size_t)MM * CC * 2;       // y [B,H,T,Dh]  16 MB

    prep_kernel<<<8192 + 3072 + 1024, 256, 0, stream>>>(x, xb, W_qkv, wqt, W_out, wot);

    gemm1_kernel<<<dim3(12, 32), 512, 0, stream>>>(xb, wqt, b_qkv, qws, kws, vtws);

    attn_kernel<<<dim3(BB * HH, 16), 256, 0, stream>>>(qws, kws, vtws, yws);

    gemm_bt_kernel<0><<<dim3(8, 64), 256, 0, stream>>>(
        yws, wot, b_out, out, nullptr, nullptr, nullptr, MM, CC, CC);
}